// Round 8
// baseline (322.025 us; speedup 1.0000x reference)
//
#include <hip/hip_runtime.h>
#include <hip/hip_bf16.h>

// Problem constants
#define B_SZ 4
#define T_SZ 1024
#define NH 16
#define L_SZ 1344          // 21*64
#define LT_COUNT 21        // L tiles of 64

typedef __attribute__((ext_vector_type(8))) short short8;   // 8 bf16
typedef __attribute__((ext_vector_type(4))) short short4v;  // 4 bf16
typedef __attribute__((ext_vector_type(4))) float floatx4;

typedef __attribute__((address_space(1))) const void gvoid;
typedef __attribute__((address_space(3))) void svoid;
#define GLD16(gp, lp) \
  __builtin_amdgcn_global_load_lds((gvoid*)(gp), (svoid*)(lp), 16, 0, 0)

static __device__ inline short bf16bits(float f) {
  return __builtin_bit_cast(short, __float2bfloat16(f));
}
static __device__ inline short4v cvt4(float4 v) {
  short4v r;
  r.x = bf16bits(v.x); r.y = bf16bits(v.y);
  r.z = bf16bits(v.z); r.w = bf16bits(v.w);
  return r;
}

// Fast fp32->bf16 pair pack: +0x8000 round-to-nearest(ties away) + v_perm.
// Inputs finite & bounded -> no overflow concern; error <= 0.5 ulp.
static __device__ inline unsigned pack_bf16_2(float a, float b) {
  unsigned ua = __builtin_bit_cast(unsigned, a) + 0x8000u;
  unsigned ub = __builtin_bit_cast(unsigned, b) + 0x8000u;
  return __builtin_amdgcn_perm(ub, ua, 0x07060302u);
}
static __device__ inline uint2 pack_bf16_4(float4 v) {
  return make_uint2(pack_bf16_2(v.x, v.y), pack_bf16_2(v.z, v.w));
}

// ---------------------------------------------------------------------------
// K/V fragment-ordered buffers (per bh = b*16+h, tc = t/64, frag f in [0,8)):
//  addr = ((bh*16+tc)*8 + f)*512 + lane*8 + j
//  K: f = ni2*2 + half -> K[t=tc*64+ni2*16+(lane&15)][d=half*32+(lane>>4)*8+j]
//  V: f = di*2 + half  -> V[t=tc*64+half*32+(lane>>4)*8+j][d=di*16+(lane&15)]
// => per tc, K frags are a contiguous 8 KB block (same for V).
// ---------------------------------------------------------------------------

// ---------------------------------------------------------------------------
// Fused prep, GRID-STRIDED at 2048 blocks. Virtual blocks [0,6144) convert
// x/wk/wv fp32->bf16; [6144,27648) compute mask bitwords. The mask dtype
// sniff (flag 0=int32, 1=int8, 2=int64) is done per-wave on the first 4 KB
// of the mask (64 lanes x 64 B). All-zero window -> f=2 (harmless: every
// interpretation yields all-false).
// ---------------------------------------------------------------------------
__global__ __launch_bounds__(256) void prep_kernel(
    const float4* __restrict__ x, const float4* __restrict__ wk,
    const float4* __restrict__ wv,
    uint2* __restrict__ xb, uint2* __restrict__ wkb, uint2* __restrict__ wvb,
    const void* __restrict__ mask, unsigned int* __restrict__ bits) {
  const int lane = threadIdx.x & 63;
  int f = -1;                              // per-wave mask dtype, sniffed lazily
  for (int vb = blockIdx.x; vb < 27648; vb += gridDim.x) {
    if (vb < 6144) {
      size_t i = (size_t)vb * 256 + threadIdx.x;
      if (i < 1048576)      xb[i] = pack_bf16_4(x[i]);               // x: 1M f4
      else if (i < 1310720) wkb[i - 1048576] = pack_bf16_4(wk[i - 1048576]);
      else                  wvb[i - 1310720] = pack_bf16_4(wv[i - 1310720]);
    } else {
      if (f < 0) {
        const uint4* mp = (const uint4*)mask;
        uint4 a = mp[lane * 4 + 0], b2 = mp[lane * 4 + 1];
        uint4 c = mp[lane * 4 + 2], d = mp[lane * 4 + 3];
        // bytes at i%4!=0 live in bits 8..31 of each dword
        unsigned oo = (a.x | a.y | a.z | a.w | b2.x | b2.y | b2.z | b2.w |
                       c.x | c.y | c.z | c.w | d.x | d.y | d.z | d.w) & 0xFFFFFF00u;
        // bytes at i%8==4 are byte0 of odd dwords (fields y, w)
        unsigned aa = (a.y | a.w | b2.y | b2.w | c.y | c.w | d.y | d.w) & 0xFFu;
        int anyo = __any(oo != 0), anya = __any(aa != 0);
        f = anyo ? 1 : (anya ? 0 : 2);
      }
      int idx = (vb - 6144) * 256 + threadIdx.x;
      bool v;
      if (f == 1)      v = ((const signed char*)mask)[idx] != 0;
      else if (f == 2) v = ((const long long*)mask)[idx] != 0;
      else             v = ((const int*)mask)[idx] != 0;
      unsigned long long bal = __ballot(v);
      if ((lane & 31) == 0) {
        unsigned int w = (lane & 32) ? (unsigned int)(bal >> 32) : (unsigned int)bal;
        bits[idx >> 5] = w;
      }
    }
  }
}

// ---------------------------------------------------------------------------
// GEMM K/V projection: tile 128(M)x64(N), BK=32, 1024 blocks (4/CU), LDS
// double-buffer (24 KB), STAGE(next)-before-compute + counted vmcnt(3) +
// raw barriers. Waves 2x2: wm = w&1 (M 64-half), wn = w>>1 (N 32-half).
// ---------------------------------------------------------------------------
__global__ __launch_bounds__(256, 4) void gemm_kv_bf16(
    const __hip_bfloat16* __restrict__ xb,
    const __hip_bfloat16* __restrict__ wkb, const __hip_bfloat16* __restrict__ wvb,
    const float* __restrict__ bk, const float* __restrict__ bv,
    __hip_bfloat16* __restrict__ k_buf, __hip_bfloat16* __restrict__ v_buf) {
  __shared__ __align__(16) __hip_bfloat16 ldsA[2][128 * 32];   // 2 x 8 KB
  __shared__ __align__(16) __hip_bfloat16 ldsB[2][64 * 32];    // 2 x 4 KB
  const int tid = threadIdx.x;
  const int lane = tid & 63, w = tid >> 6;
  const int wm = w & 1, wn = w >> 1;
  const int c15 = lane & 15, kq = lane >> 4;

  const __hip_bfloat16* A;
  const __hip_bfloat16* B;
  int TA, TB;
  if (blockIdx.z == 0) {            // K-proj: C^T[d][t] = Wk . X^T
    A = wkb; B = xb; TA = blockIdx.x >> 6; TB = blockIdx.x & 63;   // 8 x 64
  } else {                          // V-proj: C[t][d] = X . Wv^T
    A = xb; B = wvb; TA = blockIdx.x >> 4; TB = blockIdx.x & 15;   // 32 x 16
  }
  const __hip_bfloat16* Abase = A + (size_t)TA * 128 * 1024;
  const __hip_bfloat16* Bbase = B + (size_t)TB * 64 * 1024;

  floatx4 acc[4][2];
  #pragma unroll
  for (int i = 0; i < 4; ++i)
    #pragma unroll
    for (int j = 0; j < 2; ++j) acc[i][j] = (floatx4){0.f, 0.f, 0.f, 0.f};

#define GSTAGE(sb, kk) do {                                                  \
    int cA_ = w * 128 + lane;                                                \
    int rA_ = cA_ >> 2, gA_ = (cA_ & 3) ^ (rA_ & 3);                         \
    GLD16(Abase + (size_t)rA_ * 1024 + (kk) + gA_ * 8,                       \
          &ldsA[sb][(w * 128) * 8]);                                         \
    int cA2_ = cA_ + 64;                                                     \
    int rA2_ = cA2_ >> 2, gA2_ = (cA2_ & 3) ^ (rA2_ & 3);                    \
    GLD16(Abase + (size_t)rA2_ * 1024 + (kk) + gA2_ * 8,                     \
          &ldsA[sb][(w * 128 + 64) * 8]);                                    \
    int cB_ = w * 64 + lane;                                                 \
    int rB_ = cB_ >> 2, gB_ = (cB_ & 3) ^ (rB_ & 3);                         \
    GLD16(Bbase + (size_t)rB_ * 1024 + (kk) + gB_ * 8,                       \
          &ldsB[sb][(w * 64) * 8]);                                          \
  } while (0)

  GSTAGE(0, 0);
  for (int kk = 0; kk < 1024; kk += 32) {
    const int buf = (kk >> 5) & 1;
    if (kk + 32 < 1024) {
      GSTAGE(buf ^ 1, kk + 32);
      asm volatile("s_waitcnt vmcnt(3)" ::: "memory");   // current slab landed
    } else {
      asm volatile("s_waitcnt vmcnt(0)" ::: "memory");
    }
    __builtin_amdgcn_s_barrier();

    short8 af[4], bfr[2];
    #pragma unroll
    for (int mi = 0; mi < 4; ++mi) {
      int row = wm * 64 + mi * 16 + c15;
      af[mi] = *(const short8*)(&ldsA[buf][row * 32 + ((kq ^ (row & 3)) * 8)]);
    }
    #pragma unroll
    for (int ni = 0; ni < 2; ++ni) {
      int row = wn * 32 + ni * 16 + c15;
      bfr[ni] = *(const short8*)(&ldsB[buf][row * 32 + ((kq ^ (row & 3)) * 8)]);
    }
    #pragma unroll
    for (int mi = 0; mi < 4; ++mi)
      #pragma unroll
      for (int ni = 0; ni < 2; ++ni)
        acc[mi][ni] = __builtin_amdgcn_mfma_f32_16x16x32_bf16(
            af[mi], bfr[ni], acc[mi][ni], 0, 0, 0);

    asm volatile("s_waitcnt lgkmcnt(0)" ::: "memory");   // reads retired
    __builtin_amdgcn_s_barrier();                        // before re-stage
  }
#undef GSTAGE

  // ---- epilogue: write fragment-ordered k_buf / v_buf (8B per acc frag row)
  if (blockIdx.z == 0) {
    // M = d (A=wk), N = (b,t) (B=x)
    #pragma unroll
    for (int ni = 0; ni < 2; ++ni) {
      int gr = TB * 64 + wn * 32 + ni * 16 + c15;        // global x row (b,t)
      int b = gr >> 10, tc = (gr >> 6) & 15;
      int ni2 = (gr & 63) >> 4;                          // = wn*2+ni
      #pragma unroll
      for (int mi = 0; mi < 4; ++mi) {
        int d0 = TA * 128 + wm * 64 + mi * 16 + kq * 4;  // K feature dim
        int h = d0 >> 6, hd = d0 & 63;
        int half = hd >> 5, q4 = (hd >> 3) & 3, jlo = hd & 7;
        int bh = b * 16 + h;
        float4 b4 = *(const float4*)(bk + d0);
        float4 v4 = {acc[mi][ni][0] + b4.x, acc[mi][ni][1] + b4.y,
                     acc[mi][ni][2] + b4.z, acc[mi][ni][3] + b4.w};
        *(uint2*)(k_buf + ((size_t)((bh * 16 + tc) * 8 + ni2 * 2 + half)) * 512 +
                  (q4 * 16 + c15) * 8 + jlo) = pack_bf16_4(v4);
      }
    }
  } else {
    // M = (b,t) (A=x), N = d (B=wv)
    #pragma unroll
    for (int ni = 0; ni < 2; ++ni) {
      int d = TB * 64 + wn * 32 + ni * 16 + c15;         // V feature dim
      int h = d >> 6;
      int di = (d & 63) >> 4;                            // = wn*2+ni
      float bias = bv[d];
      #pragma unroll
      for (int mi = 0; mi < 4; ++mi) {
        int gr = TA * 128 + wm * 64 + mi * 16 + kq * 4;  // global x row (b,t)
        int b = gr >> 10, tc = (gr >> 6) & 15;
        int tl = gr & 63;
        int half = tl >> 5, q4 = (tl >> 3) & 3, jlo = tl & 7;
        int bh = b * 16 + h;
        float4 v4 = {acc[mi][ni][0] + bias, acc[mi][ni][1] + bias,
                     acc[mi][ni][2] + bias, acc[mi][ni][3] + bias};
        *(uint2*)(v_buf + ((size_t)((bh * 16 + tc) * 8 + di * 2 + half)) * 512 +
                  (q4 * 16 + c15) * 8 + jlo) = pack_bf16_4(v4);
      }
    }
  }
}

// ---------------------------------------------------------------------------
// flash attention, round-8: 512-thread blocks (8 waves, 1 l-group each =
// 128 latents), 704 blocks (64 bh x 11; tail block has waves 4-7 idle).
// Rationale: attn was pinned at 63-67 us across 3 structural variants; the
// invariant cost is per-BLOCK overhead (each block re-reads its bh's full
// 256 KB K/V from L2, pays 32 barriers + staging issue). Halving block
// count halves K/V global traffic (344->180 MB) and staging/barrier cost
// per latent, and 704 blocks fit ONE residency generation (<=3 blocks/CU
// at LDS 48 KB). Per-wave regs unchanged (~60) -- no r1-style spill.
// Staging duty: EVERY wave (incl. idle tail waves) stages 1 KB K + 1 KB V
// per tc and follows the identical vmcnt ledger (idle waves load a clamped
// mask word): a wave that staged data must drain its own vmcnt before the
// barrier, else readers see unlanded LDS.
// Ledger (3 vmem/iter: K,M,V; prologue K,V,M):
//   B1 vmcnt(3): outstanding {K(n),M(n),V(n),K(n+1)} -> retires K(n).
//   B2 vmcnt(3): outstanding {M(n),V(n),K(n+1),M(n+1),V(n+1)} -> M(n),V(n).
//   Tail: vmcnt(2) / vmcnt(0).
// WAR on LDS dbuf slots: K(n-1) readers are lgkm-retired before their wave
// reaches B2(n-1) < STAGE_K(n+1); V(n-1) readers retired before B1(n) <
// STAGE_V(n+1). l-sums via MFMA ones-trick. Fixed-max softmax.
// ---------------------------------------------------------------------------
__global__ __launch_bounds__(512, 6) void attn_kernel(
    const float* __restrict__ latent_q,            // fp32, flat (H, L, dh)
    const __hip_bfloat16* __restrict__ k_buf,      // fragment-ordered
    const __hip_bfloat16* __restrict__ v_buf,      // fragment-ordered
    const unsigned int* __restrict__ mbits,        // (b*L+l)*32 + t/32
    float* __restrict__ out) {                     // fp32 (b*L+l)*1024 + h*64+d
  __shared__ __align__(16) __hip_bfloat16 ldsK[2][4096];    // 16 KB dbuf
  __shared__ __align__(16) __hip_bfloat16 ldsV[2][4096];    // 16 KB dbuf
  __shared__ __align__(16) __hip_bfloat16 pbuf[8][1024];    // 16 KB, swizzled

  const int tid = threadIdx.x;
  const int lane = tid & 63;
  const int w = tid >> 6;                          // wave id = l-group id [0,8)
  int bid = blockIdx.x;
  int xcd = bid & 7, j = bid >> 3;                 // j in [0,88)
  int bh = xcd * 8 + j / 11;                       // all blocks of one bh -> one XCD
  int sb = j % 11;                                 // 128-latent superblock
  int h = bh & 15, b = bh >> 4;
  const int q4 = lane >> 4, c15 = lane & 15;
  const int c7 = c15 & 7;
  const int l0 = sb * 128;                         // block's latent base
  const int lg = l0 + w * 16;                      // this wave's group base
  const bool has = lg < L_SZ;                      // tail block: waves 4-7 idle
  const int lrow = has ? lg : 0;                   // clamped (keeps loads valid
                                                   //  and vmcnt ledger uniform)

  // ---- Q^T B-frag for THIS wave's group, pre-scaled by 16^-0.5 * log2(e)
  const float QS = 0.25f * 1.44269504089f;
  short8 qf[2];
  {
    const float* qp = latent_q + ((size_t)(h * L_SZ + lrow + c15)) * 64 + q4 * 8;
    float4 a0 = *(const float4*)(qp);
    float4 a1 = *(const float4*)(qp + 4);
    float4 a2 = *(const float4*)(qp + 32);
    float4 a3 = *(const float4*)(qp + 36);
    a0.x *= QS; a0.y *= QS; a0.z *= QS; a0.w *= QS;
    a1.x *= QS; a1.y *= QS; a1.z *= QS; a1.w *= QS;
    a2.x *= QS; a2.y *= QS; a2.z *= QS; a2.w *= QS;
    a3.x *= QS; a3.y *= QS; a3.z *= QS; a3.w *= QS;
    short4v t0 = cvt4(a0), t1 = cvt4(a1), t2 = cvt4(a2), t3 = cvt4(a3);
    qf[0] = (short8){t0.x, t0.y, t0.z, t0.w, t1.x, t1.y, t1.z, t1.w};
    qf[1] = (short8){t2.x, t2.y, t2.z, t2.w, t3.x, t3.y, t3.z, t3.w};
  }

  const short ob16 = (short)0x3F80;                // bf16 1.0
  const short8 ones8 = (short8){ob16, ob16, ob16, ob16, ob16, ob16, ob16, ob16};
  const floatx4 zero4 = (floatx4){0.f, 0.f, 0.f, 0.f};

  floatx4 lacc = zero4;                            // l row-sums (all rows equal)
  floatx4 o_acc[4];
  #pragma unroll
  for (int di = 0; di < 4; ++di) o_acc[di] = zero4;

  const __hip_bfloat16* kb = k_buf + (size_t)bh * 65536;   // 16 tc * 8 * 512
  const __hip_bfloat16* vb = v_buf + (size_t)bh * 65536;
  __hip_bfloat16* pw = pbuf[w];
  // this lane's mask row (8B word per tc); clamped for idle waves
  const unsigned int* mrow = mbits + ((size_t)(b * L_SZ + lrow + c15)) * 32;

  // each wave stages 1 KB of K (and 1 KB of V) per tc: 8 waves cover 8 KB.
#define STAGE_K(sbuf, tcn) \
    GLD16(kb + (size_t)(tcn) * 4096 + w * 512 + lane * 8, &ldsK[sbuf][w * 512])
#define STAGE_V(sbuf, tcn) \
    GLD16(vb + (size_t)(tcn) * 4096 + w * 512 + lane * 8, &ldsV[sbuf][w * 512])

  STAGE_K(0, 0);                                   // prologue: K0, V0, M0
  STAGE_V(0, 0);
  uint2 mw_cur = *(const uint2*)(mrow);

  for (int tc = 0; tc < 16; ++tc) {
    const int buf = tc & 1;
    // ---- B1: K(tc) visible (V(tc) + mask may still be in flight)
    if (tc < 15) {
      STAGE_K(buf ^ 1, tc + 1);
      asm volatile("s_waitcnt vmcnt(3)" ::: "memory");  // K(tc) drained
    } else {
      asm volatile("s_waitcnt vmcnt(2)" ::: "memory");
    }
    __builtin_amdgcn_s_barrier();

    uint2 mw_nxt = mw_cur;
    if (tc < 15) mw_nxt = *(const uint2*)(mrow + (tc + 1) * 2);

    // ---- K A-frags from LDS, QK^T (idle waves skip; no LDS hazard)
    floatx4 s[4];
    if (has) {
      short8 kf[2][4];
      #pragma unroll
      for (int half = 0; half < 2; ++half)
        #pragma unroll
        for (int ni = 0; ni < 4; ++ni)
          kf[half][ni] = *(const short8*)(&ldsK[buf][(ni * 2 + half) * 512 + lane * 8]);
      __builtin_amdgcn_s_setprio(1);
      #pragma unroll
      for (int ni = 0; ni < 4; ++ni)
        s[ni] = __builtin_amdgcn_mfma_f32_16x16x32_bf16(kf[0][ni], qf[0], zero4, 0, 0, 0);
      #pragma unroll
      for (int ni = 0; ni < 4; ++ni)
        s[ni] = __builtin_amdgcn_mfma_f32_16x16x32_bf16(kf[1][ni], qf[1], s[ni], 0, 0, 0);
      __builtin_amdgcn_s_setprio(0);
    }

    // ---- B2: V(tc) visible (all waves stage + wait, compute role or not)
    if (tc < 15) {
      STAGE_V(buf ^ 1, tc + 1);
      asm volatile("s_waitcnt vmcnt(3)" ::: "memory");  // V(tc) drained
    } else {
      asm volatile("s_waitcnt vmcnt(0)" ::: "memory");
    }
    __builtin_amdgcn_s_barrier();

    if (has) {
      // ---- V A-frags (latency hides under softmax VALU below)
      short8 vf[2][4];
      #pragma unroll
      for (int half = 0; half < 2; ++half)
        #pragma unroll
        for (int di = 0; di < 4; ++di)
          vf[half][di] = *(const short8*)(&ldsV[buf][(di * 2 + half) * 512 + lane * 8]);

      // ---- masked exp2, pack to pbuf[w] (XOR chunk swizzle, stride 64)
      #pragma unroll
      for (int ni = 0; ni < 4; ++ni) {
        unsigned mword = (ni >= 2) ? mw_cur.y : mw_cur.x;
        float4 p4;
        #pragma unroll
        for (int r = 0; r < 4; ++r) {
          float e = exp2f(s[ni][r]);
          int sh = (ni & 1) * 16 + q4 * 4 + r;
          ((float*)&p4)[r] = ((mword >> sh) & 1) ? e : 0.f;
        }
        int pc = (ni * 2 + (q4 >> 1)) ^ c7;        // phys 16B chunk
        *(uint2*)(pw + c15 * 64 + pc * 8 + (q4 & 1) * 4) = pack_bf16_4(p4);
      }

      // ---- P^T B-frags; O^T += V^T.P^T; l += ones.P^T (in-wave DS order)
      int pc0 = q4 ^ c7;
      short8 pf0 = *(const short8*)(pw + c15 * 64 + pc0 * 8);
      short8 pf1 = *(const short8*)(pw + c15 * 64 + (pc0 ^ 4) * 8);
      __builtin_amdgcn_s_setprio(1);
      #pragma unroll
      for (int di = 0; di < 4; ++di)
        o_acc[di] = __builtin_amdgcn_mfma_f32_16x16x32_bf16(vf[0][di], pf0, o_acc[di], 0, 0, 0);
      #pragma unroll
      for (int di = 0; di < 4; ++di)
        o_acc[di] = __builtin_amdgcn_mfma_f32_16x16x32_bf16(vf[1][di], pf1, o_acc[di], 0, 0, 0);
      lacc = __builtin_amdgcn_mfma_f32_16x16x32_bf16(ones8, pf0, lacc, 0, 0, 0);
      lacc = __builtin_amdgcn_mfma_f32_16x16x32_bf16(ones8, pf1, lacc, 0, 0, 0);
      __builtin_amdgcn_s_setprio(0);
    }

    mw_cur = mw_nxt;
  }
#undef STAGE_K
#undef STAGE_V

  // ---- normalize, store (all rows of lacc equal l[c15]; all-masked -> 0)
  if (has) {
    float la = lacc[0];
    float inv = (la > 0.f) ? 1.f / la : 0.f;
    float* ob = out + ((size_t)(b * L_SZ + lrow + c15)) * 1024 + h * 64;
    #pragma unroll
    for (int di = 0; di < 4; ++di) {
      float4 o4 = {o_acc[di][0] * inv, o_acc[di][1] * inv,
                   o_acc[di][2] * inv, o_acc[di][3] * inv};
      *(float4*)(ob + di * 16 + q4 * 4) = o4;
    }
  }
}

// ---------------------------------------------------------------------------
extern "C" void kernel_launch(void* const* d_in, const int* in_sizes, int n_in,
                              void* d_out, int out_size, void* d_ws, size_t ws_size,
                              hipStream_t stream) {
  const float* x      = (const float*)d_in[0];
  const void* ch_mask = d_in[1];
  const float* lq     = (const float*)d_in[2];
  const float* wk     = (const float*)d_in[3];
  const float* bk     = (const float*)d_in[4];
  const float* wv     = (const float*)d_in[5];
  const float* bv     = (const float*)d_in[6];
  float* out = (float*)d_out;

  // ws layout (total 16.75 MB -- proven-safe)
  char* ws = (char*)d_ws;
  unsigned int* mbits   = (unsigned int*)ws;                         // 688 KB
  __hip_bfloat16* k_buf = (__hip_bfloat16*)(ws + 786432);            // 8 MB
  __hip_bfloat16* v_buf = (__hip_bfloat16*)(ws + 786432 + 8388608);  // 8 MB

  // d_out (22 MB fp32) doubles as scratch for bf16 inputs (12 MB) -- it is
  // only written for real in attn's epilogue, after gemm_kv consumed these.
  __hip_bfloat16* xb  = (__hip_bfloat16*)d_out;                      // 8 MB
  __hip_bfloat16* wkb = xb + 4 * 1024 * 1024;                        // 2 MB
  __hip_bfloat16* wvb = wkb + 1024 * 1024;                           // 2 MB

  prep_kernel<<<2048, 256, 0, stream>>>(
      (const float4*)x, (const float4*)wk, (const float4*)wv,
      (uint2*)xb, (uint2*)wkb, (uint2*)wvb,
      ch_mask, mbits);
  gemm_kv_bf16<<<dim3(512, 1, 2), 256, 0, stream>>>(xb, wkb, wvb, bk, bv, k_buf, v_buf);

  attn_kernel<<<8 * 88, 512, 0, stream>>>(lq, k_buf, v_buf, mbits, out);
}

// Round 9
// 182.550 us; speedup vs baseline: 1.7640x; 1.7640x over previous
//
#include <hip/hip_runtime.h>
#include <hip/hip_bf16.h>

// Problem constants
#define B_SZ 4
#define T_SZ 1024
#define NH 16
#define L_SZ 1344          // 21*64
#define LT_COUNT 21        // L tiles of 64

typedef __attribute__((ext_vector_type(8))) short short8;   // 8 bf16
typedef __attribute__((ext_vector_type(4))) short short4v;  // 4 bf16
typedef __attribute__((ext_vector_type(4))) float floatx4;

typedef __attribute__((address_space(1))) const void gvoid;
typedef __attribute__((address_space(3))) void svoid;
#define GLD16(gp, lp) \
  __builtin_amdgcn_global_load_lds((gvoid*)(gp), (svoid*)(lp), 16, 0, 0)

static __device__ inline short bf16bits(float f) {
  return __builtin_bit_cast(short, __float2bfloat16(f));
}
static __device__ inline short4v cvt4(float4 v) {
  short4v r;
  r.x = bf16bits(v.x); r.y = bf16bits(v.y);
  r.z = bf16bits(v.z); r.w = bf16bits(v.w);
  return r;
}

// Fast fp32->bf16 pair pack: +0x8000 round-to-nearest(ties away) + v_perm.
// Inputs finite & bounded -> no overflow concern; error <= 0.5 ulp.
static __device__ inline unsigned pack_bf16_2(float a, float b) {
  unsigned ua = __builtin_bit_cast(unsigned, a) + 0x8000u;
  unsigned ub = __builtin_bit_cast(unsigned, b) + 0x8000u;
  return __builtin_amdgcn_perm(ub, ua, 0x07060302u);
}
static __device__ inline uint2 pack_bf16_4(float4 v) {
  return make_uint2(pack_bf16_2(v.x, v.y), pack_bf16_2(v.z, v.w));
}

// ---------------------------------------------------------------------------
// K/V fragment-ordered buffers (per bh = b*16+h, tc = t/64, frag f in [0,8)):
//  addr = ((bh*16+tc)*8 + f)*512 + lane*8 + j
//  K: f = ni2*2 + half -> K[t=tc*64+ni2*16+(lane&15)][d=half*32+(lane>>4)*8+j]
//  V: f = di*2 + half  -> V[t=tc*64+half*32+(lane>>4)*8+j][d=di*16+(lane&15)]
// => per tc, K frags are a contiguous 8 KB block (same for V).
// ---------------------------------------------------------------------------

// ---------------------------------------------------------------------------
// Fused prep, GRID-STRIDED at 2048 blocks. Virtual blocks [0,6144) convert
// x/wk/wv fp32->bf16; [6144,27648) compute mask bitwords. The mask dtype
// sniff (flag 0=int32, 1=int8, 2=int64) is done per-wave on the first 4 KB
// of the mask (64 lanes x 64 B). All-zero window -> f=2 (harmless: every
// interpretation yields all-false).
// ---------------------------------------------------------------------------
__global__ __launch_bounds__(256) void prep_kernel(
    const float4* __restrict__ x, const float4* __restrict__ wk,
    const float4* __restrict__ wv,
    uint2* __restrict__ xb, uint2* __restrict__ wkb, uint2* __restrict__ wvb,
    const void* __restrict__ mask, unsigned int* __restrict__ bits) {
  const int lane = threadIdx.x & 63;
  int f = -1;                              // per-wave mask dtype, sniffed lazily
  for (int vb = blockIdx.x; vb < 27648; vb += gridDim.x) {
    if (vb < 6144) {
      size_t i = (size_t)vb * 256 + threadIdx.x;
      if (i < 1048576)      xb[i] = pack_bf16_4(x[i]);               // x: 1M f4
      else if (i < 1310720) wkb[i - 1048576] = pack_bf16_4(wk[i - 1048576]);
      else                  wvb[i - 1310720] = pack_bf16_4(wv[i - 1310720]);
    } else {
      if (f < 0) {
        const uint4* mp = (const uint4*)mask;
        uint4 a = mp[lane * 4 + 0], b2 = mp[lane * 4 + 1];
        uint4 c = mp[lane * 4 + 2], d = mp[lane * 4 + 3];
        // bytes at i%4!=0 live in bits 8..31 of each dword
        unsigned oo = (a.x | a.y | a.z | a.w | b2.x | b2.y | b2.z | b2.w |
                       c.x | c.y | c.z | c.w | d.x | d.y | d.z | d.w) & 0xFFFFFF00u;
        // bytes at i%8==4 are byte0 of odd dwords (fields y, w)
        unsigned aa = (a.y | a.w | b2.y | b2.w | c.y | c.w | d.y | d.w) & 0xFFu;
        int anyo = __any(oo != 0), anya = __any(aa != 0);
        f = anyo ? 1 : (anya ? 0 : 2);
      }
      int idx = (vb - 6144) * 256 + threadIdx.x;
      bool v;
      if (f == 1)      v = ((const signed char*)mask)[idx] != 0;
      else if (f == 2) v = ((const long long*)mask)[idx] != 0;
      else             v = ((const int*)mask)[idx] != 0;
      unsigned long long bal = __ballot(v);
      if ((lane & 31) == 0) {
        unsigned int w = (lane & 32) ? (unsigned int)(bal >> 32) : (unsigned int)bal;
        bits[idx >> 5] = w;
      }
    }
  }
}

// ---------------------------------------------------------------------------
// GEMM K/V projection: tile 128(M)x64(N), BK=32, 1024 blocks (4/CU), LDS
// double-buffer (24 KB), STAGE(next)-before-compute + counted vmcnt(3) +
// raw barriers. Waves 2x2: wm = w&1 (M 64-half), wn = w>>1 (N 32-half).
// ---------------------------------------------------------------------------
__global__ __launch_bounds__(256, 4) void gemm_kv_bf16(
    const __hip_bfloat16* __restrict__ xb,
    const __hip_bfloat16* __restrict__ wkb, const __hip_bfloat16* __restrict__ wvb,
    const float* __restrict__ bk, const float* __restrict__ bv,
    __hip_bfloat16* __restrict__ k_buf, __hip_bfloat16* __restrict__ v_buf) {
  __shared__ __align__(16) __hip_bfloat16 ldsA[2][128 * 32];   // 2 x 8 KB
  __shared__ __align__(16) __hip_bfloat16 ldsB[2][64 * 32];    // 2 x 4 KB
  const int tid = threadIdx.x;
  const int lane = tid & 63, w = tid >> 6;
  const int wm = w & 1, wn = w >> 1;
  const int c15 = lane & 15, kq = lane >> 4;

  const __hip_bfloat16* A;
  const __hip_bfloat16* B;
  int TA, TB;
  if (blockIdx.z == 0) {            // K-proj: C^T[d][t] = Wk . X^T
    A = wkb; B = xb; TA = blockIdx.x >> 6; TB = blockIdx.x & 63;   // 8 x 64
  } else {                          // V-proj: C[t][d] = X . Wv^T
    A = xb; B = wvb; TA = blockIdx.x >> 4; TB = blockIdx.x & 15;   // 32 x 16
  }
  const __hip_bfloat16* Abase = A + (size_t)TA * 128 * 1024;
  const __hip_bfloat16* Bbase = B + (size_t)TB * 64 * 1024;

  floatx4 acc[4][2];
  #pragma unroll
  for (int i = 0; i < 4; ++i)
    #pragma unroll
    for (int j = 0; j < 2; ++j) acc[i][j] = (floatx4){0.f, 0.f, 0.f, 0.f};

#define GSTAGE(sb, kk) do {                                                  \
    int cA_ = w * 128 + lane;                                                \
    int rA_ = cA_ >> 2, gA_ = (cA_ & 3) ^ (rA_ & 3);                         \
    GLD16(Abase + (size_t)rA_ * 1024 + (kk) + gA_ * 8,                       \
          &ldsA[sb][(w * 128) * 8]);                                         \
    int cA2_ = cA_ + 64;                                                     \
    int rA2_ = cA2_ >> 2, gA2_ = (cA2_ & 3) ^ (rA2_ & 3);                    \
    GLD16(Abase + (size_t)rA2_ * 1024 + (kk) + gA2_ * 8,                     \
          &ldsA[sb][(w * 128 + 64) * 8]);                                    \
    int cB_ = w * 64 + lane;                                                 \
    int rB_ = cB_ >> 2, gB_ = (cB_ & 3) ^ (rB_ & 3);                         \
    GLD16(Bbase + (size_t)rB_ * 1024 + (kk) + gB_ * 8,                       \
          &ldsB[sb][(w * 64) * 8]);                                          \
  } while (0)

  GSTAGE(0, 0);
  for (int kk = 0; kk < 1024; kk += 32) {
    const int buf = (kk >> 5) & 1;
    if (kk + 32 < 1024) {
      GSTAGE(buf ^ 1, kk + 32);
      asm volatile("s_waitcnt vmcnt(3)" ::: "memory");   // current slab landed
    } else {
      asm volatile("s_waitcnt vmcnt(0)" ::: "memory");
    }
    __builtin_amdgcn_s_barrier();

    short8 af[4], bfr[2];
    #pragma unroll
    for (int mi = 0; mi < 4; ++mi) {
      int row = wm * 64 + mi * 16 + c15;
      af[mi] = *(const short8*)(&ldsA[buf][row * 32 + ((kq ^ (row & 3)) * 8)]);
    }
    #pragma unroll
    for (int ni = 0; ni < 2; ++ni) {
      int row = wn * 32 + ni * 16 + c15;
      bfr[ni] = *(const short8*)(&ldsB[buf][row * 32 + ((kq ^ (row & 3)) * 8)]);
    }
    #pragma unroll
    for (int mi = 0; mi < 4; ++mi)
      #pragma unroll
      for (int ni = 0; ni < 2; ++ni)
        acc[mi][ni] = __builtin_amdgcn_mfma_f32_16x16x32_bf16(
            af[mi], bfr[ni], acc[mi][ni], 0, 0, 0);

    asm volatile("s_waitcnt lgkmcnt(0)" ::: "memory");   // reads retired
    __builtin_amdgcn_s_barrier();                        // before re-stage
  }
#undef GSTAGE

  // ---- epilogue: write fragment-ordered k_buf / v_buf (8B per acc frag row)
  if (blockIdx.z == 0) {
    // M = d (A=wk), N = (b,t) (B=x)
    #pragma unroll
    for (int ni = 0; ni < 2; ++ni) {
      int gr = TB * 64 + wn * 32 + ni * 16 + c15;        // global x row (b,t)
      int b = gr >> 10, tc = (gr >> 6) & 15;
      int ni2 = (gr & 63) >> 4;                          // = wn*2+ni
      #pragma unroll
      for (int mi = 0; mi < 4; ++mi) {
        int d0 = TA * 128 + wm * 64 + mi * 16 + kq * 4;  // K feature dim
        int h = d0 >> 6, hd = d0 & 63;
        int half = hd >> 5, q4 = (hd >> 3) & 3, jlo = hd & 7;
        int bh = b * 16 + h;
        float4 b4 = *(const float4*)(bk + d0);
        float4 v4 = {acc[mi][ni][0] + b4.x, acc[mi][ni][1] + b4.y,
                     acc[mi][ni][2] + b4.z, acc[mi][ni][3] + b4.w};
        *(uint2*)(k_buf + ((size_t)((bh * 16 + tc) * 8 + ni2 * 2 + half)) * 512 +
                  (q4 * 16 + c15) * 8 + jlo) = pack_bf16_4(v4);
      }
    }
  } else {
    // M = (b,t) (A=x), N = d (B=wv)
    #pragma unroll
    for (int ni = 0; ni < 2; ++ni) {
      int d = TB * 64 + wn * 32 + ni * 16 + c15;         // V feature dim
      int h = d >> 6;
      int di = (d & 63) >> 4;                            // = wn*2+ni
      float bias = bv[d];
      #pragma unroll
      for (int mi = 0; mi < 4; ++mi) {
        int gr = TA * 128 + wm * 64 + mi * 16 + kq * 4;  // global x row (b,t)
        int b = gr >> 10, tc = (gr >> 6) & 15;
        int tl = gr & 63;
        int half = tl >> 5, q4 = (tl >> 3) & 3, jlo = tl & 7;
        int bh = b * 16 + h;
        float4 v4 = {acc[mi][ni][0] + bias, acc[mi][ni][1] + bias,
                     acc[mi][ni][2] + bias, acc[mi][ni][3] + bias};
        *(uint2*)(v_buf + ((size_t)((bh * 16 + tc) * 8 + di * 2 + half)) * 512 +
                  (q4 * 16 + c15) * 8 + jlo) = pack_bf16_4(v4);
      }
    }
  }
}

// ---------------------------------------------------------------------------
// flash attention: round-7 structure (best measured: 63.4 us), 256 threads,
// 4 waves, GROUP-split. Round-8's 512-thread variant is REVERTED: its
// __launch_bounds__(512,6) capped VGPRs at ~42 -> ~780 MB scratch spill.
// Round-9 softmax VALU cuts (attn is VALU-inst bound, ~440 inst/wave-tc):
//  (a) exp2 via inline-asm v_exp_f32 -- 1 TRANS inst, bypasses any OCML
//      guard sequence. Scores pre-scaled by log2(e), |s| small: safe.
//  (b) sign-spread masking: pre-shift mask word by q4*4 (per-lane shift paid
//      once), then per element keep = ((int)(msh<<(31-pos))>>31) with
//      compile-time pos, AND onto fp32 bits of e. 3 const-shift insts/elem,
//      no cmp/cndmask; masked-out -> exact 0.0f.
// Ledger unchanged from r7 (5 vmem/iter: K2,M1,V2; B1/B2 vmcnt(5), tail 3/0).
// l-sums via MFMA ones-trick. s_setprio around MFMA clusters (T5).
// ---------------------------------------------------------------------------
__global__ __launch_bounds__(256, 4) void attn_kernel(
    const float* __restrict__ latent_q,            // fp32, flat (H, L, dh)
    const __hip_bfloat16* __restrict__ k_buf,      // fragment-ordered
    const __hip_bfloat16* __restrict__ v_buf,      // fragment-ordered
    const unsigned int* __restrict__ mbits,        // (b*L+l)*32 + t/32
    float* __restrict__ out) {                     // fp32 (b*L+l)*1024 + h*64+d
  __shared__ __align__(16) __hip_bfloat16 ldsK[2][4096];    // 16 KB dbuf
  __shared__ __align__(16) __hip_bfloat16 ldsV[2][4096];    // 16 KB dbuf
  __shared__ __align__(16) __hip_bfloat16 pbuf[4][1024];    // 8 KB, swizzled

  const int tid = threadIdx.x;
  const int lane = tid & 63;
  const int w = tid >> 6;                          // wave id = l-group id
  int bid = blockIdx.x;
  int xcd = bid & 7, j = bid >> 3;                 // j in [0,168)
  int bh = xcd * 8 + j / LT_COUNT;                 // all lt of one bh -> one XCD
  int lt = j % LT_COUNT;
  int h = bh & 15, b = bh >> 4;
  const int q4 = lane >> 4, c15 = lane & 15;
  const int c7 = c15 & 7;
  const int l0 = lt * 64;                          // block's latent base

  // ---- Q^T B-frag for THIS wave's group, pre-scaled by 16^-0.5 * log2(e)
  const float QS = 0.25f * 1.44269504089f;
  short8 qf[2];
  {
    const float* qp = latent_q + ((size_t)(h * L_SZ + l0 + w * 16 + c15)) * 64 + q4 * 8;
    float4 a0 = *(const float4*)(qp);
    float4 a1 = *(const float4*)(qp + 4);
    float4 a2 = *(const float4*)(qp + 32);
    float4 a3 = *(const float4*)(qp + 36);
    a0.x *= QS; a0.y *= QS; a0.z *= QS; a0.w *= QS;
    a1.x *= QS; a1.y *= QS; a1.z *= QS; a1.w *= QS;
    a2.x *= QS; a2.y *= QS; a2.z *= QS; a2.w *= QS;
    a3.x *= QS; a3.y *= QS; a3.z *= QS; a3.w *= QS;
    short4v t0 = cvt4(a0), t1 = cvt4(a1), t2 = cvt4(a2), t3 = cvt4(a3);
    qf[0] = (short8){t0.x, t0.y, t0.z, t0.w, t1.x, t1.y, t1.z, t1.w};
    qf[1] = (short8){t2.x, t2.y, t2.z, t2.w, t3.x, t3.y, t3.z, t3.w};
  }

  const short ob16 = (short)0x3F80;                // bf16 1.0
  const short8 ones8 = (short8){ob16, ob16, ob16, ob16, ob16, ob16, ob16, ob16};
  const floatx4 zero4 = (floatx4){0.f, 0.f, 0.f, 0.f};

  floatx4 lacc = zero4;                            // l row-sums (all rows equal)
  floatx4 o_acc[4];
  #pragma unroll
  for (int di = 0; di < 4; ++di) o_acc[di] = zero4;

  const __hip_bfloat16* kb = k_buf + (size_t)bh * 65536;   // 16 tc * 8 * 512
  const __hip_bfloat16* vb = v_buf + (size_t)bh * 65536;
  __hip_bfloat16* pw = pbuf[w];
  // this lane's mask row (8B word per tc); 16 rows/wave = 16 cache lines
  const unsigned int* mrow = mbits + ((size_t)(b * L_SZ + l0 + w * 16 + c15)) * 32;

#define STAGE_K(sb, tcn) do {                                               \
    const __hip_bfloat16* gk_ = kb + (size_t)(tcn) * 4096;                  \
    int o0_ = w * 512 + lane * 8;                                           \
    GLD16(gk_ + o0_,        &ldsK[sb][w * 512]);                            \
    GLD16(gk_ + 2048 + o0_, &ldsK[sb][2048 + w * 512]);                     \
  } while (0)
#define STAGE_V(sb, tcn) do {                                               \
    const __hip_bfloat16* gv_ = vb + (size_t)(tcn) * 4096;                  \
    int o0_ = w * 512 + lane * 8;                                           \
    GLD16(gv_ + o0_,        &ldsV[sb][w * 512]);                            \
    GLD16(gv_ + 2048 + o0_, &ldsV[sb][2048 + w * 512]);                     \
  } while (0)

  uint2 mw_cur = *(const uint2*)(mrow);            // tc=0 mask word
  STAGE_K(0, 0);                                   // prologue prefetch
  STAGE_V(0, 0);

  for (int tc = 0; tc < 16; ++tc) {
    const int buf = tc & 1;
    // ---- B1: K(tc) visible (V(tc) may still be in flight)
    if (tc < 15) {
      STAGE_K(buf ^ 1, tc + 1);
      asm volatile("s_waitcnt vmcnt(5)" ::: "memory");  // K(tc) drained
    } else {
      asm volatile("s_waitcnt vmcnt(3)" ::: "memory");
    }
    __builtin_amdgcn_s_barrier();

    uint2 mw_nxt = mw_cur;
    if (tc < 15) mw_nxt = *(const uint2*)(mrow + (tc + 1) * 2);

    // ---- K A-frags from LDS, QK^T
    short8 kf[2][4];
    #pragma unroll
    for (int half = 0; half < 2; ++half)
      #pragma unroll
      for (int ni = 0; ni < 4; ++ni)
        kf[half][ni] = *(const short8*)(&ldsK[buf][(ni * 2 + half) * 512 + lane * 8]);
    floatx4 s[4];
    __builtin_amdgcn_s_setprio(1);
    #pragma unroll
    for (int ni = 0; ni < 4; ++ni)
      s[ni] = __builtin_amdgcn_mfma_f32_16x16x32_bf16(kf[0][ni], qf[0], zero4, 0, 0, 0);
    #pragma unroll
    for (int ni = 0; ni < 4; ++ni)
      s[ni] = __builtin_amdgcn_mfma_f32_16x16x32_bf16(kf[1][ni], qf[1], s[ni], 0, 0, 0);
    __builtin_amdgcn_s_setprio(0);

    // ---- B2: V(tc) visible; also proves all waves done reading K frags
    if (tc < 15) {
      STAGE_V(buf ^ 1, tc + 1);
      asm volatile("s_waitcnt vmcnt(5)" ::: "memory");  // V(tc) drained
    } else {
      asm volatile("s_waitcnt vmcnt(0)" ::: "memory");
    }
    __builtin_amdgcn_s_barrier();

    // ---- V A-frags (latency hides under softmax VALU below)
    short8 vf[2][4];
    #pragma unroll
    for (int half = 0; half < 2; ++half)
      #pragma unroll
      for (int di = 0; di < 4; ++di)
        vf[half][di] = *(const short8*)(&ldsV[buf][(di * 2 + half) * 512 + lane * 8]);

    // ---- softmax: asm v_exp_f32 + sign-spread mask AND, pack to pbuf[w]
    unsigned mshx = mw_cur.x >> (q4 * 4);          // per-lane shift paid once
    unsigned mshy = mw_cur.y >> (q4 * 4);
    #pragma unroll
    for (int ni = 0; ni < 4; ++ni) {
      unsigned msh = (ni >= 2) ? mshy : mshx;
      float4 p4;
      #pragma unroll
      for (int r = 0; r < 4; ++r) {
        float e;
        asm("v_exp_f32 %0, %1" : "=v"(e) : "v"(s[ni][r]));
        const int pos = (ni & 1) * 16 + r;         // compile-time constant
        unsigned keep = (unsigned)((int)(msh << (31 - pos)) >> 31);
        ((float*)&p4)[r] = __builtin_bit_cast(
            float, __builtin_bit_cast(unsigned, e) & keep);
      }
      int pc = (ni * 2 + (q4 >> 1)) ^ c7;          // phys 16B chunk
      *(uint2*)(pw + c15 * 64 + pc * 8 + (q4 & 1) * 4) = pack_bf16_4(p4);
    }

    // ---- P^T B-frags; O^T += V^T.P^T; l += ones.P^T (in-wave DS order)
    int pc0 = q4 ^ c7;
    short8 pf0 = *(const short8*)(pw + c15 * 64 + pc0 * 8);
    short8 pf1 = *(const short8*)(pw + c15 * 64 + (pc0 ^ 4) * 8);
    __builtin_amdgcn_s_setprio(1);
    #pragma unroll
    for (int di = 0; di < 4; ++di)
      o_acc[di] = __builtin_amdgcn_mfma_f32_16x16x32_bf16(vf[0][di], pf0, o_acc[di], 0, 0, 0);
    #pragma unroll
    for (int di = 0; di < 4; ++di)
      o_acc[di] = __builtin_amdgcn_mfma_f32_16x16x32_bf16(vf[1][di], pf1, o_acc[di], 0, 0, 0);
    lacc = __builtin_amdgcn_mfma_f32_16x16x32_bf16(ones8, pf0, lacc, 0, 0, 0);
    lacc = __builtin_amdgcn_mfma_f32_16x16x32_bf16(ones8, pf1, lacc, 0, 0, 0);
    __builtin_amdgcn_s_setprio(0);

    mw_cur = mw_nxt;
  }
#undef STAGE_K
#undef STAGE_V

  // ---- normalize, store (all rows of lacc equal l[c15]; all-masked -> 0)
  float la = lacc[0];
  float inv = (la > 0.f) ? 1.f / la : 0.f;
  float* ob = out + ((size_t)(b * L_SZ + l0 + w * 16 + c15)) * 1024 + h * 64;
  #pragma unroll
  for (int di = 0; di < 4; ++di) {
    float4 o4 = {o_acc[di][0] * inv, o_acc[di][1] * inv,
                 o_acc[di][2] * inv, o_acc[di][3] * inv};
    *(float4*)(ob + di * 16 + q4 * 4) = o4;
  }
}

// ---------------------------------------------------------------------------
extern "C" void kernel_launch(void* const* d_in, const int* in_sizes, int n_in,
                              void* d_out, int out_size, void* d_ws, size_t ws_size,
                              hipStream_t stream) {
  const float* x      = (const float*)d_in[0];
  const void* ch_mask = d_in[1];
  const float* lq     = (const float*)d_in[2];
  const float* wk     = (const float*)d_in[3];
  const float* bk     = (const float*)d_in[4];
  const float* wv     = (const float*)d_in[5];
  const float* bv     = (const float*)d_in[6];
  float* out = (float*)d_out;

  // ws layout (total 16.75 MB -- proven-safe)
  char* ws = (char*)d_ws;
  unsigned int* mbits   = (unsigned int*)ws;                         // 688 KB
  __hip_bfloat16* k_buf = (__hip_bfloat16*)(ws + 786432);            // 8 MB
  __hip_bfloat16* v_buf = (__hip_bfloat16*)(ws + 786432 + 8388608);  // 8 MB

  // d_out (22 MB fp32) doubles as scratch for bf16 inputs (12 MB) -- it is
  // only written for real in attn's epilogue, after gemm_kv consumed these.
  __hip_bfloat16* xb  = (__hip_bfloat16*)d_out;                      // 8 MB
  __hip_bfloat16* wkb = xb + 4 * 1024 * 1024;                        // 2 MB
  __hip_bfloat16* wvb = wkb + 1024 * 1024;                           // 2 MB

  prep_kernel<<<2048, 256, 0, stream>>>(
      (const float4*)x, (const float4*)wk, (const float4*)wv,
      (uint2*)xb, (uint2*)wkb, (uint2*)wvb,
      ch_mask, mbits);
  gemm_kv_bf16<<<dim3(512, 1, 2), 256, 0, stream>>>(xb, wkb, wvb, bk, bv, k_buf, v_buf);

  attn_kernel<<<8 * 168, 256, 0, stream>>>(lq, k_buf, v_buf, mbits, out);
}

// Round 10
// 179.400 us; speedup vs baseline: 1.7950x; 1.0176x over previous
//
#include <hip/hip_runtime.h>
#include <hip/hip_bf16.h>

// Problem constants
#define B_SZ 4
#define T_SZ 1024
#define NH 16
#define L_SZ 1344          // 21*64
#define LT_COUNT 21        // L tiles of 64

typedef __attribute__((ext_vector_type(8))) short short8;   // 8 bf16
typedef __attribute__((ext_vector_type(4))) short short4v;  // 4 bf16
typedef __attribute__((ext_vector_type(4))) float floatx4;

typedef __attribute__((address_space(1))) const void gvoid;
typedef __attribute__((address_space(3))) void svoid;
#define GLD16(gp, lp) \
  __builtin_amdgcn_global_load_lds((gvoid*)(gp), (svoid*)(lp), 16, 0, 0)

static __device__ inline short bf16bits(float f) {
  return __builtin_bit_cast(short, __float2bfloat16(f));
}
static __device__ inline short4v cvt4(float4 v) {
  short4v r;
  r.x = bf16bits(v.x); r.y = bf16bits(v.y);
  r.z = bf16bits(v.z); r.w = bf16bits(v.w);
  return r;
}

// Fast fp32->bf16 pair pack: +0x8000 round-to-nearest(ties away) + v_perm.
// Inputs finite & bounded -> no overflow concern; error <= 0.5 ulp.
static __device__ inline unsigned pack_bf16_2(float a, float b) {
  unsigned ua = __builtin_bit_cast(unsigned, a) + 0x8000u;
  unsigned ub = __builtin_bit_cast(unsigned, b) + 0x8000u;
  return __builtin_amdgcn_perm(ub, ua, 0x07060302u);
}
static __device__ inline uint2 pack_bf16_4(float4 v) {
  return make_uint2(pack_bf16_2(v.x, v.y), pack_bf16_2(v.z, v.w));
}

// ---------------------------------------------------------------------------
// K/V fragment-ordered buffers (per bh = b*16+h, tc = t/64, frag f in [0,8)):
//  addr = ((bh*16+tc)*8 + f)*512 + lane*8 + j
//  K: f = ni2*2 + half -> K[t=tc*64+ni2*16+(lane&15)][d=half*32+(lane>>4)*8+j]
//  V: f = di*2 + half  -> V[t=tc*64+half*32+(lane>>4)*8+j][d=di*16+(lane&15)]
// => per tc, K frags are a contiguous 8 KB block (same for V).
// ---------------------------------------------------------------------------

// ---------------------------------------------------------------------------
// Fused prep, GRID-STRIDED at 2048 blocks. Virtual blocks [0,6144) convert
// x/wk/wv fp32->bf16; [6144,27648) compute mask bitwords. The mask dtype
// sniff (flag 0=int32, 1=int8, 2=int64) is done per-wave on the first 4 KB
// of the mask (64 lanes x 64 B). All-zero window -> f=2 (harmless: every
// interpretation yields all-false).
// ---------------------------------------------------------------------------
__global__ __launch_bounds__(256) void prep_kernel(
    const float4* __restrict__ x, const float4* __restrict__ wk,
    const float4* __restrict__ wv,
    uint2* __restrict__ xb, uint2* __restrict__ wkb, uint2* __restrict__ wvb,
    const void* __restrict__ mask, unsigned int* __restrict__ bits) {
  const int lane = threadIdx.x & 63;
  int f = -1;                              // per-wave mask dtype, sniffed lazily
  for (int vb = blockIdx.x; vb < 27648; vb += gridDim.x) {
    if (vb < 6144) {
      size_t i = (size_t)vb * 256 + threadIdx.x;
      if (i < 1048576)      xb[i] = pack_bf16_4(x[i]);               // x: 1M f4
      else if (i < 1310720) wkb[i - 1048576] = pack_bf16_4(wk[i - 1048576]);
      else                  wvb[i - 1310720] = pack_bf16_4(wv[i - 1310720]);
    } else {
      if (f < 0) {
        const uint4* mp = (const uint4*)mask;
        uint4 a = mp[lane * 4 + 0], b2 = mp[lane * 4 + 1];
        uint4 c = mp[lane * 4 + 2], d = mp[lane * 4 + 3];
        // bytes at i%4!=0 live in bits 8..31 of each dword
        unsigned oo = (a.x | a.y | a.z | a.w | b2.x | b2.y | b2.z | b2.w |
                       c.x | c.y | c.z | c.w | d.x | d.y | d.z | d.w) & 0xFFFFFF00u;
        // bytes at i%8==4 are byte0 of odd dwords (fields y, w)
        unsigned aa = (a.y | a.w | b2.y | b2.w | c.y | c.w | d.y | d.w) & 0xFFu;
        int anyo = __any(oo != 0), anya = __any(aa != 0);
        f = anyo ? 1 : (anya ? 0 : 2);
      }
      int idx = (vb - 6144) * 256 + threadIdx.x;
      bool v;
      if (f == 1)      v = ((const signed char*)mask)[idx] != 0;
      else if (f == 2) v = ((const long long*)mask)[idx] != 0;
      else             v = ((const int*)mask)[idx] != 0;
      unsigned long long bal = __ballot(v);
      if ((lane & 31) == 0) {
        unsigned int w = (lane & 32) ? (unsigned int)(bal >> 32) : (unsigned int)bal;
        bits[idx >> 5] = w;
      }
    }
  }
}

// ---------------------------------------------------------------------------
// GEMM K/V projection: tile 128(M)x64(N), BK=32, 1024 blocks (4/CU), LDS
// double-buffer (24 KB), STAGE(next)-before-compute + counted vmcnt(3) +
// raw barriers. Waves 2x2: wm = w&1 (M 64-half), wn = w>>1 (N 32-half).
// ---------------------------------------------------------------------------
__global__ __launch_bounds__(256, 4) void gemm_kv_bf16(
    const __hip_bfloat16* __restrict__ xb,
    const __hip_bfloat16* __restrict__ wkb, const __hip_bfloat16* __restrict__ wvb,
    const float* __restrict__ bk, const float* __restrict__ bv,
    __hip_bfloat16* __restrict__ k_buf, __hip_bfloat16* __restrict__ v_buf) {
  __shared__ __align__(16) __hip_bfloat16 ldsA[2][128 * 32];   // 2 x 8 KB
  __shared__ __align__(16) __hip_bfloat16 ldsB[2][64 * 32];    // 2 x 4 KB
  const int tid = threadIdx.x;
  const int lane = tid & 63, w = tid >> 6;
  const int wm = w & 1, wn = w >> 1;
  const int c15 = lane & 15, kq = lane >> 4;

  const __hip_bfloat16* A;
  const __hip_bfloat16* B;
  int TA, TB;
  if (blockIdx.z == 0) {            // K-proj: C^T[d][t] = Wk . X^T
    A = wkb; B = xb; TA = blockIdx.x >> 6; TB = blockIdx.x & 63;   // 8 x 64
  } else {                          // V-proj: C[t][d] = X . Wv^T
    A = xb; B = wvb; TA = blockIdx.x >> 4; TB = blockIdx.x & 15;   // 32 x 16
  }
  const __hip_bfloat16* Abase = A + (size_t)TA * 128 * 1024;
  const __hip_bfloat16* Bbase = B + (size_t)TB * 64 * 1024;

  floatx4 acc[4][2];
  #pragma unroll
  for (int i = 0; i < 4; ++i)
    #pragma unroll
    for (int j = 0; j < 2; ++j) acc[i][j] = (floatx4){0.f, 0.f, 0.f, 0.f};

#define GSTAGE(sb, kk) do {                                                  \
    int cA_ = w * 128 + lane;                                                \
    int rA_ = cA_ >> 2, gA_ = (cA_ & 3) ^ (rA_ & 3);                         \
    GLD16(Abase + (size_t)rA_ * 1024 + (kk) + gA_ * 8,                       \
          &ldsA[sb][(w * 128) * 8]);                                         \
    int cA2_ = cA_ + 64;                                                     \
    int rA2_ = cA2_ >> 2, gA2_ = (cA2_ & 3) ^ (rA2_ & 3);                    \
    GLD16(Abase + (size_t)rA2_ * 1024 + (kk) + gA2_ * 8,                     \
          &ldsA[sb][(w * 128 + 64) * 8]);                                    \
    int cB_ = w * 64 + lane;                                                 \
    int rB_ = cB_ >> 2, gB_ = (cB_ & 3) ^ (rB_ & 3);                         \
    GLD16(Bbase + (size_t)rB_ * 1024 + (kk) + gB_ * 8,                       \
          &ldsB[sb][(w * 64) * 8]);                                          \
  } while (0)

  GSTAGE(0, 0);
  for (int kk = 0; kk < 1024; kk += 32) {
    const int buf = (kk >> 5) & 1;
    if (kk + 32 < 1024) {
      GSTAGE(buf ^ 1, kk + 32);
      asm volatile("s_waitcnt vmcnt(3)" ::: "memory");   // current slab landed
    } else {
      asm volatile("s_waitcnt vmcnt(0)" ::: "memory");
    }
    __builtin_amdgcn_s_barrier();

    short8 af[4], bfr[2];
    #pragma unroll
    for (int mi = 0; mi < 4; ++mi) {
      int row = wm * 64 + mi * 16 + c15;
      af[mi] = *(const short8*)(&ldsA[buf][row * 32 + ((kq ^ (row & 3)) * 8)]);
    }
    #pragma unroll
    for (int ni = 0; ni < 2; ++ni) {
      int row = wn * 32 + ni * 16 + c15;
      bfr[ni] = *(const short8*)(&ldsB[buf][row * 32 + ((kq ^ (row & 3)) * 8)]);
    }
    #pragma unroll
    for (int mi = 0; mi < 4; ++mi)
      #pragma unroll
      for (int ni = 0; ni < 2; ++ni)
        acc[mi][ni] = __builtin_amdgcn_mfma_f32_16x16x32_bf16(
            af[mi], bfr[ni], acc[mi][ni], 0, 0, 0);

    asm volatile("s_waitcnt lgkmcnt(0)" ::: "memory");   // reads retired
    __builtin_amdgcn_s_barrier();                        // before re-stage
  }
#undef GSTAGE

  // ---- epilogue: write fragment-ordered k_buf / v_buf (8B per acc frag row)
  if (blockIdx.z == 0) {
    // M = d (A=wk), N = (b,t) (B=x)
    #pragma unroll
    for (int ni = 0; ni < 2; ++ni) {
      int gr = TB * 64 + wn * 32 + ni * 16 + c15;        // global x row (b,t)
      int b = gr >> 10, tc = (gr >> 6) & 15;
      int ni2 = (gr & 63) >> 4;                          // = wn*2+ni
      #pragma unroll
      for (int mi = 0; mi < 4; ++mi) {
        int d0 = TA * 128 + wm * 64 + mi * 16 + kq * 4;  // K feature dim
        int h = d0 >> 6, hd = d0 & 63;
        int half = hd >> 5, q4 = (hd >> 3) & 3, jlo = hd & 7;
        int bh = b * 16 + h;
        float4 b4 = *(const float4*)(bk + d0);
        float4 v4 = {acc[mi][ni][0] + b4.x, acc[mi][ni][1] + b4.y,
                     acc[mi][ni][2] + b4.z, acc[mi][ni][3] + b4.w};
        *(uint2*)(k_buf + ((size_t)((bh * 16 + tc) * 8 + ni2 * 2 + half)) * 512 +
                  (q4 * 16 + c15) * 8 + jlo) = pack_bf16_4(v4);
      }
    }
  } else {
    // M = (b,t) (A=x), N = d (B=wv)
    #pragma unroll
    for (int ni = 0; ni < 2; ++ni) {
      int d = TB * 64 + wn * 32 + ni * 16 + c15;         // V feature dim
      int h = d >> 6;
      int di = (d & 63) >> 4;                            // = wn*2+ni
      float bias = bv[d];
      #pragma unroll
      for (int mi = 0; mi < 4; ++mi) {
        int gr = TA * 128 + wm * 64 + mi * 16 + kq * 4;  // global x row (b,t)
        int b = gr >> 10, tc = (gr >> 6) & 15;
        int tl = gr & 63;
        int half = tl >> 5, q4 = (tl >> 3) & 3, jlo = tl & 7;
        int bh = b * 16 + h;
        float4 v4 = {acc[mi][ni][0] + bias, acc[mi][ni][1] + bias,
                     acc[mi][ni][2] + bias, acc[mi][ni][3] + bias};
        *(uint2*)(v_buf + ((size_t)((bh * 16 + tc) * 8 + di * 2 + half)) * 512 +
                  (q4 * 16 + c15) * 8 + jlo) = pack_bf16_4(v4);
      }
    }
  }
}

// ---------------------------------------------------------------------------
// flash attention, round-10: 2 l-groups per wave (128 latents/block),
// 704 blocks = 64 bh x 11 (tail block sb=10 has only g0: block-uniform).
// Rationale (r9 counters): LDS traffic was the largest attn term
// (1.72 GB ~ 25 us chip-wide); kf/vf now loaded ONCE per tc and reused for
// both groups -> LDS bytes/latent -40%, staging + barriers + K/V L2
// traffic per latent halved. 704 blocks at (256,3) = 2.75 blocks/CU ->
// ONE residency generation (no ragged tail). VGPR peak ~130 < 170 cap
// (r1/r8 spill lesson: WRITE_SIZE > 21504 is the spill sentinel).
// Ledger (6 vmem/iter: K2 | M2, V2; prologue K2,V2,M2):
//   B1 vmcnt(6): retires K(n).  B2 vmcnt(6): retires M(n), V(n).
//   Tail tc=15: B1 vmcnt(4), B2 vmcnt(0).
// pbuf reused g0->g1 within a tc (in-wave DS ordering). Tail g1 computes on
// clamped (valid, finite) Q/mask rows and skips only the store.
// l-sums via MFMA ones-trick. asm v_exp_f32 + sign-spread masking (r9).
// ---------------------------------------------------------------------------
__global__ __launch_bounds__(256, 3) void attn_kernel(
    const float* __restrict__ latent_q,            // fp32, flat (H, L, dh)
    const __hip_bfloat16* __restrict__ k_buf,      // fragment-ordered
    const __hip_bfloat16* __restrict__ v_buf,      // fragment-ordered
    const unsigned int* __restrict__ mbits,        // (b*L+l)*32 + t/32
    float* __restrict__ out) {                     // fp32 (b*L+l)*1024 + h*64+d
  __shared__ __align__(16) __hip_bfloat16 ldsK[2][4096];    // 16 KB dbuf
  __shared__ __align__(16) __hip_bfloat16 ldsV[2][4096];    // 16 KB dbuf
  __shared__ __align__(16) __hip_bfloat16 pbuf[4][1024];    // 8 KB, swizzled

  const int tid = threadIdx.x;
  const int lane = tid & 63;
  const int w = tid >> 6;                          // wave id
  int bid = blockIdx.x;
  int xcd = bid & 7, j = bid >> 3;                 // j in [0,88)
  int bh = xcd * 8 + j / 11;                       // all blocks of one bh -> one XCD
  int sb = j % 11;                                 // 128-latent superblock
  int h = bh & 15, b = bh >> 4;
  const int q4 = lane >> 4, c15 = lane & 15;
  const int c7 = c15 & 7;
  const int l0 = sb * 128;
  const bool hasg1 = (sb < 10);                    // block-uniform
  const int lg0 = l0 + w * 16;
  const int lg1 = hasg1 ? (l0 + 64 + w * 16) : lg0;   // clamped for tail

  // ---- Q^T B-frags for both groups, pre-scaled by 16^-0.5 * log2(e)
  const float QS = 0.25f * 1.44269504089f;
  short8 qf[2][2];
  #pragma unroll
  for (int g = 0; g < 2; ++g) {
    int lg = g ? lg1 : lg0;
    const float* qp = latent_q + ((size_t)(h * L_SZ + lg + c15)) * 64 + q4 * 8;
    float4 a0 = *(const float4*)(qp);
    float4 a1 = *(const float4*)(qp + 4);
    float4 a2 = *(const float4*)(qp + 32);
    float4 a3 = *(const float4*)(qp + 36);
    a0.x *= QS; a0.y *= QS; a0.z *= QS; a0.w *= QS;
    a1.x *= QS; a1.y *= QS; a1.z *= QS; a1.w *= QS;
    a2.x *= QS; a2.y *= QS; a2.z *= QS; a2.w *= QS;
    a3.x *= QS; a3.y *= QS; a3.z *= QS; a3.w *= QS;
    short4v t0 = cvt4(a0), t1 = cvt4(a1), t2 = cvt4(a2), t3 = cvt4(a3);
    qf[g][0] = (short8){t0.x, t0.y, t0.z, t0.w, t1.x, t1.y, t1.z, t1.w};
    qf[g][1] = (short8){t2.x, t2.y, t2.z, t2.w, t3.x, t3.y, t3.z, t3.w};
  }

  const short ob16 = (short)0x3F80;                // bf16 1.0
  const short8 ones8 = (short8){ob16, ob16, ob16, ob16, ob16, ob16, ob16, ob16};
  const floatx4 zero4 = (floatx4){0.f, 0.f, 0.f, 0.f};

  floatx4 lacc[2];
  floatx4 o_acc[2][4];
  #pragma unroll
  for (int g = 0; g < 2; ++g) {
    lacc[g] = zero4;
    #pragma unroll
    for (int di = 0; di < 4; ++di) o_acc[g][di] = zero4;
  }

  const __hip_bfloat16* kb = k_buf + (size_t)bh * 65536;   // 16 tc * 8 * 512
  const __hip_bfloat16* vb = v_buf + (size_t)bh * 65536;
  __hip_bfloat16* pw = pbuf[w];
  const unsigned int* mrow0 = mbits + ((size_t)(b * L_SZ + lg0 + c15)) * 32;
  const unsigned int* mrow1 = mbits + ((size_t)(b * L_SZ + lg1 + c15)) * 32;

#define STAGE_K(sb_, tcn) do {                                              \
    const __hip_bfloat16* gk_ = kb + (size_t)(tcn) * 4096;                  \
    int o0_ = w * 512 + lane * 8;                                           \
    GLD16(gk_ + o0_,        &ldsK[sb_][w * 512]);                           \
    GLD16(gk_ + 2048 + o0_, &ldsK[sb_][2048 + w * 512]);                    \
  } while (0)
#define STAGE_V(sb_, tcn) do {                                              \
    const __hip_bfloat16* gv_ = vb + (size_t)(tcn) * 4096;                  \
    int o0_ = w * 512 + lane * 8;                                           \
    GLD16(gv_ + o0_,        &ldsV[sb_][w * 512]);                           \
    GLD16(gv_ + 2048 + o0_, &ldsV[sb_][2048 + w * 512]);                    \
  } while (0)

  STAGE_K(0, 0);                                   // prologue: K2, V2, M2
  STAGE_V(0, 0);
  uint2 mw0 = *(const uint2*)(mrow0);
  uint2 mw1 = *(const uint2*)(mrow1);

  for (int tc = 0; tc < 16; ++tc) {
    const int buf = tc & 1;
    // ---- B1: K(tc) visible (M/V may still be in flight)
    if (tc < 15) {
      STAGE_K(buf ^ 1, tc + 1);
      asm volatile("s_waitcnt vmcnt(6)" ::: "memory");
    } else {
      asm volatile("s_waitcnt vmcnt(4)" ::: "memory");
    }
    __builtin_amdgcn_s_barrier();

    uint2 mn0 = mw0, mn1 = mw1;
    if (tc < 15) {
      mn0 = *(const uint2*)(mrow0 + (tc + 1) * 2);
      mn1 = *(const uint2*)(mrow1 + (tc + 1) * 2);
    }

    // ---- K A-frags from LDS once; QK^T for both groups
    short8 kf[2][4];
    #pragma unroll
    for (int half = 0; half < 2; ++half)
      #pragma unroll
      for (int ni = 0; ni < 4; ++ni)
        kf[half][ni] = *(const short8*)(&ldsK[buf][(ni * 2 + half) * 512 + lane * 8]);
    floatx4 s[2][4];
    __builtin_amdgcn_s_setprio(1);
    #pragma unroll
    for (int g = 0; g < 2; ++g) {
      #pragma unroll
      for (int ni = 0; ni < 4; ++ni)
        s[g][ni] = __builtin_amdgcn_mfma_f32_16x16x32_bf16(kf[0][ni], qf[g][0], zero4, 0, 0, 0);
      #pragma unroll
      for (int ni = 0; ni < 4; ++ni)
        s[g][ni] = __builtin_amdgcn_mfma_f32_16x16x32_bf16(kf[1][ni], qf[g][1], s[g][ni], 0, 0, 0);
    }
    __builtin_amdgcn_s_setprio(0);

    // ---- B2: V(tc) + masks(tc) visible
    if (tc < 15) {
      STAGE_V(buf ^ 1, tc + 1);
      asm volatile("s_waitcnt vmcnt(6)" ::: "memory");
    } else {
      asm volatile("s_waitcnt vmcnt(0)" ::: "memory");
    }
    __builtin_amdgcn_s_barrier();

    // ---- V A-frags once for both groups
    short8 vf[2][4];
    #pragma unroll
    for (int half = 0; half < 2; ++half)
      #pragma unroll
      for (int di = 0; di < 4; ++di)
        vf[half][di] = *(const short8*)(&ldsV[buf][(di * 2 + half) * 512 + lane * 8]);

    // ---- per group: softmax -> pbuf -> PV (pbuf reused: in-wave DS order)
    #pragma unroll
    for (int g = 0; g < 2; ++g) {
      uint2 mw = g ? mw1 : mw0;
      unsigned mshx = mw.x >> (q4 * 4);            // per-lane shift paid once
      unsigned mshy = mw.y >> (q4 * 4);
      #pragma unroll
      for (int ni = 0; ni < 4; ++ni) {
        unsigned msh = (ni >= 2) ? mshy : mshx;
        float4 p4;
        #pragma unroll
        for (int r = 0; r < 4; ++r) {
          float e;
          asm("v_exp_f32 %0, %1" : "=v"(e) : "v"(s[g][ni][r]));
          const int pos = (ni & 1) * 16 + r;       // compile-time constant
          unsigned keep = (unsigned)((int)(msh << (31 - pos)) >> 31);
          ((float*)&p4)[r] = __builtin_bit_cast(
              float, __builtin_bit_cast(unsigned, e) & keep);
        }
        int pc = (ni * 2 + (q4 >> 1)) ^ c7;        // phys 16B chunk
        *(uint2*)(pw + c15 * 64 + pc * 8 + (q4 & 1) * 4) = pack_bf16_4(p4);
      }
      int pc0 = q4 ^ c7;
      short8 pf0 = *(const short8*)(pw + c15 * 64 + pc0 * 8);
      short8 pf1 = *(const short8*)(pw + c15 * 64 + (pc0 ^ 4) * 8);
      __builtin_amdgcn_s_setprio(1);
      #pragma unroll
      for (int di = 0; di < 4; ++di)
        o_acc[g][di] = __builtin_amdgcn_mfma_f32_16x16x32_bf16(vf[0][di], pf0, o_acc[g][di], 0, 0, 0);
      #pragma unroll
      for (int di = 0; di < 4; ++di)
        o_acc[g][di] = __builtin_amdgcn_mfma_f32_16x16x32_bf16(vf[1][di], pf1, o_acc[g][di], 0, 0, 0);
      lacc[g] = __builtin_amdgcn_mfma_f32_16x16x32_bf16(ones8, pf0, lacc[g], 0, 0, 0);
      lacc[g] = __builtin_amdgcn_mfma_f32_16x16x32_bf16(ones8, pf1, lacc[g], 0, 0, 0);
      __builtin_amdgcn_s_setprio(0);
    }

    mw0 = mn0; mw1 = mn1;
  }
#undef STAGE_K
#undef STAGE_V

  // ---- normalize, store (all rows of lacc equal l[c15]; all-masked -> 0)
  #pragma unroll
  for (int g = 0; g < 2; ++g) {
    if (g == 1 && !hasg1) break;                   // block-uniform
    int lg = g ? lg1 : lg0;
    float la = lacc[g][0];
    float inv = (la > 0.f) ? 1.f / la : 0.f;
    float* ob = out + ((size_t)(b * L_SZ + lg + c15)) * 1024 + h * 64;
    #pragma unroll
    for (int di = 0; di < 4; ++di) {
      float4 o4 = {o_acc[g][di][0] * inv, o_acc[g][di][1] * inv,
                   o_acc[g][di][2] * inv, o_acc[g][di][3] * inv};
      *(float4*)(ob + di * 16 + q4 * 4) = o4;
    }
  }
}

// ---------------------------------------------------------------------------
extern "C" void kernel_launch(void* const* d_in, const int* in_sizes, int n_in,
                              void* d_out, int out_size, void* d_ws, size_t ws_size,
                              hipStream_t stream) {
  const float* x      = (const float*)d_in[0];
  const void* ch_mask = d_in[1];
  const float* lq     = (const float*)d_in[2];
  const float* wk     = (const float*)d_in[3];
  const float* bk     = (const float*)d_in[4];
  const float* wv     = (const float*)d_in[5];
  const float* bv     = (const float*)d_in[6];
  float* out = (float*)d_out;

  // ws layout (total 16.75 MB -- proven-safe)
  char* ws = (char*)d_ws;
  unsigned int* mbits   = (unsigned int*)ws;                         // 688 KB
  __hip_bfloat16* k_buf = (__hip_bfloat16*)(ws + 786432);            // 8 MB
  __hip_bfloat16* v_buf = (__hip_bfloat16*)(ws + 786432 + 8388608);  // 8 MB

  // d_out (22 MB fp32) doubles as scratch for bf16 inputs (12 MB) -- it is
  // only written for real in attn's epilogue, after gemm_kv consumed these.
  __hip_bfloat16* xb  = (__hip_bfloat16*)d_out;                      // 8 MB
  __hip_bfloat16* wkb = xb + 4 * 1024 * 1024;                        // 2 MB
  __hip_bfloat16* wvb = wkb + 1024 * 1024;                           // 2 MB

  prep_kernel<<<2048, 256, 0, stream>>>(
      (const float4*)x, (const float4*)wk, (const float4*)wv,
      (uint2*)xb, (uint2*)wkb, (uint2*)wvb,
      ch_mask, mbits);
  gemm_kv_bf16<<<dim3(512, 1, 2), 256, 0, stream>>>(xb, wkb, wvb, bk, bv, k_buf, v_buf);

  attn_kernel<<<8 * 88, 256, 0, stream>>>(lq, k_buf, v_buf, mbits, out);
}

// Round 11
// 178.976 us; speedup vs baseline: 1.7993x; 1.0024x over previous
//
#include <hip/hip_runtime.h>
#include <hip/hip_bf16.h>

// Problem constants
#define B_SZ 4
#define T_SZ 1024
#define NH 16
#define L_SZ 1344          // 21*64
#define LT_COUNT 21        // L tiles of 64

typedef __attribute__((ext_vector_type(8))) short short8;   // 8 bf16
typedef __attribute__((ext_vector_type(4))) short short4v;  // 4 bf16
typedef __attribute__((ext_vector_type(4))) float floatx4;

typedef __attribute__((address_space(1))) const void gvoid;
typedef __attribute__((address_space(3))) void svoid;
#define GLD16(gp, lp) \
  __builtin_amdgcn_global_load_lds((gvoid*)(gp), (svoid*)(lp), 16, 0, 0)

static __device__ inline short bf16bits(float f) {
  return __builtin_bit_cast(short, __float2bfloat16(f));
}
static __device__ inline short4v cvt4(float4 v) {
  short4v r;
  r.x = bf16bits(v.x); r.y = bf16bits(v.y);
  r.z = bf16bits(v.z); r.w = bf16bits(v.w);
  return r;
}

// Fast fp32->bf16 pair pack: +0x8000 round-to-nearest(ties away) + v_perm.
// Inputs finite & bounded -> no overflow concern; error <= 0.5 ulp.
static __device__ inline unsigned pack_bf16_2(float a, float b) {
  unsigned ua = __builtin_bit_cast(unsigned, a) + 0x8000u;
  unsigned ub = __builtin_bit_cast(unsigned, b) + 0x8000u;
  return __builtin_amdgcn_perm(ub, ua, 0x07060302u);
}
static __device__ inline uint2 pack_bf16_4(float4 v) {
  return make_uint2(pack_bf16_2(v.x, v.y), pack_bf16_2(v.z, v.w));
}

// ---------------------------------------------------------------------------
// K/V fragment-ordered buffers (per bh = b*16+h, tc = t/64, frag f in [0,8)):
//  addr = ((bh*16+tc)*8 + f)*512 + lane*8 + j
//  K: f = ni2*2 + half -> K[t=tc*64+ni2*16+(lane&15)][d=half*32+(lane>>4)*8+j]
//  V: f = di*2 + half  -> V[t=tc*64+half*32+(lane>>4)*8+j][d=di*16+(lane&15)]
// => per tc, K frags are a contiguous 8 KB block (same for V).
// ---------------------------------------------------------------------------

// ---------------------------------------------------------------------------
// Fused prep, GRID-STRIDED at 2048 blocks. Virtual blocks [0,6144) convert
// x/wk/wv fp32->bf16; [6144,27648) compute mask bitwords. The mask dtype
// sniff (flag 0=int32, 1=int8, 2=int64) is done per-wave on the first 4 KB
// of the mask (64 lanes x 64 B). All-zero window -> f=2 (harmless: every
// interpretation yields all-false).
// ---------------------------------------------------------------------------
__global__ __launch_bounds__(256) void prep_kernel(
    const float4* __restrict__ x, const float4* __restrict__ wk,
    const float4* __restrict__ wv,
    uint2* __restrict__ xb, uint2* __restrict__ wkb, uint2* __restrict__ wvb,
    const void* __restrict__ mask, unsigned int* __restrict__ bits) {
  const int lane = threadIdx.x & 63;
  int f = -1;                              // per-wave mask dtype, sniffed lazily
  for (int vb = blockIdx.x; vb < 27648; vb += gridDim.x) {
    if (vb < 6144) {
      size_t i = (size_t)vb * 256 + threadIdx.x;
      if (i < 1048576)      xb[i] = pack_bf16_4(x[i]);               // x: 1M f4
      else if (i < 1310720) wkb[i - 1048576] = pack_bf16_4(wk[i - 1048576]);
      else                  wvb[i - 1310720] = pack_bf16_4(wv[i - 1310720]);
    } else {
      if (f < 0) {
        const uint4* mp = (const uint4*)mask;
        uint4 a = mp[lane * 4 + 0], b2 = mp[lane * 4 + 1];
        uint4 c = mp[lane * 4 + 2], d = mp[lane * 4 + 3];
        // bytes at i%4!=0 live in bits 8..31 of each dword
        unsigned oo = (a.x | a.y | a.z | a.w | b2.x | b2.y | b2.z | b2.w |
                       c.x | c.y | c.z | c.w | d.x | d.y | d.z | d.w) & 0xFFFFFF00u;
        // bytes at i%8==4 are byte0 of odd dwords (fields y, w)
        unsigned aa = (a.y | a.w | b2.y | b2.w | c.y | c.w | d.y | d.w) & 0xFFu;
        int anyo = __any(oo != 0), anya = __any(aa != 0);
        f = anyo ? 1 : (anya ? 0 : 2);
      }
      int idx = (vb - 6144) * 256 + threadIdx.x;
      bool v;
      if (f == 1)      v = ((const signed char*)mask)[idx] != 0;
      else if (f == 2) v = ((const long long*)mask)[idx] != 0;
      else             v = ((const int*)mask)[idx] != 0;
      unsigned long long bal = __ballot(v);
      if ((lane & 31) == 0) {
        unsigned int w = (lane & 32) ? (unsigned int)(bal >> 32) : (unsigned int)bal;
        bits[idx >> 5] = w;
      }
    }
  }
}

// ---------------------------------------------------------------------------
// GEMM K/V projection: tile 128(M)x64(N), BK=32, 1024 blocks (4/CU), LDS
// double-buffer (24 KB). Round-11: SINGLE barrier per K-step (was 2; 64->32
// barriers): vmcnt(0) -> barrier -> GSTAGE(next) -> ds_reads+MFMA.
// WAR proof: slot buf^1 is staged AFTER the barrier; its last readers
// (iter kk-32) lgkm-consumed their ds_reads before passing that barrier.
// Visibility: slab staged one full compute phase earlier; issuer drains
// vmcnt(0) before the barrier. Waves 2x2: wm=w&1 (M), wn=w>>1 (N).
// ---------------------------------------------------------------------------
__global__ __launch_bounds__(256, 4) void gemm_kv_bf16(
    const __hip_bfloat16* __restrict__ xb,
    const __hip_bfloat16* __restrict__ wkb, const __hip_bfloat16* __restrict__ wvb,
    const float* __restrict__ bk, const float* __restrict__ bv,
    __hip_bfloat16* __restrict__ k_buf, __hip_bfloat16* __restrict__ v_buf) {
  __shared__ __align__(16) __hip_bfloat16 ldsA[2][128 * 32];   // 2 x 8 KB
  __shared__ __align__(16) __hip_bfloat16 ldsB[2][64 * 32];    // 2 x 4 KB
  const int tid = threadIdx.x;
  const int lane = tid & 63, w = tid >> 6;
  const int wm = w & 1, wn = w >> 1;
  const int c15 = lane & 15, kq = lane >> 4;

  const __hip_bfloat16* A;
  const __hip_bfloat16* B;
  int TA, TB;
  if (blockIdx.z == 0) {            // K-proj: C^T[d][t] = Wk . X^T
    A = wkb; B = xb; TA = blockIdx.x >> 6; TB = blockIdx.x & 63;   // 8 x 64
  } else {                          // V-proj: C[t][d] = X . Wv^T
    A = xb; B = wvb; TA = blockIdx.x >> 4; TB = blockIdx.x & 15;   // 32 x 16
  }
  const __hip_bfloat16* Abase = A + (size_t)TA * 128 * 1024;
  const __hip_bfloat16* Bbase = B + (size_t)TB * 64 * 1024;

  floatx4 acc[4][2];
  #pragma unroll
  for (int i = 0; i < 4; ++i)
    #pragma unroll
    for (int j = 0; j < 2; ++j) acc[i][j] = (floatx4){0.f, 0.f, 0.f, 0.f};

#define GSTAGE(sb, kk) do {                                                  \
    int cA_ = w * 128 + lane;                                                \
    int rA_ = cA_ >> 2, gA_ = (cA_ & 3) ^ (rA_ & 3);                         \
    GLD16(Abase + (size_t)rA_ * 1024 + (kk) + gA_ * 8,                       \
          &ldsA[sb][(w * 128) * 8]);                                         \
    int cA2_ = cA_ + 64;                                                     \
    int rA2_ = cA2_ >> 2, gA2_ = (cA2_ & 3) ^ (rA2_ & 3);                    \
    GLD16(Abase + (size_t)rA2_ * 1024 + (kk) + gA2_ * 8,                     \
          &ldsA[sb][(w * 128 + 64) * 8]);                                    \
    int cB_ = w * 64 + lane;                                                 \
    int rB_ = cB_ >> 2, gB_ = (cB_ & 3) ^ (rB_ & 3);                         \
    GLD16(Bbase + (size_t)rB_ * 1024 + (kk) + gB_ * 8,                       \
          &ldsB[sb][(w * 64) * 8]);                                          \
  } while (0)

  GSTAGE(0, 0);
  for (int kk = 0; kk < 1024; kk += 32) {
    const int buf = (kk >> 5) & 1;
    asm volatile("s_waitcnt vmcnt(0)" ::: "memory");     // slab(kk) landed
    __builtin_amdgcn_s_barrier();                        // visible; prev reads done
    if (kk + 32 < 1024) GSTAGE(buf ^ 1, kk + 32);        // stage next slab

    short8 af[4], bfr[2];
    #pragma unroll
    for (int mi = 0; mi < 4; ++mi) {
      int row = wm * 64 + mi * 16 + c15;
      af[mi] = *(const short8*)(&ldsA[buf][row * 32 + ((kq ^ (row & 3)) * 8)]);
    }
    #pragma unroll
    for (int ni = 0; ni < 2; ++ni) {
      int row = wn * 32 + ni * 16 + c15;
      bfr[ni] = *(const short8*)(&ldsB[buf][row * 32 + ((kq ^ (row & 3)) * 8)]);
    }
    #pragma unroll
    for (int mi = 0; mi < 4; ++mi)
      #pragma unroll
      for (int ni = 0; ni < 2; ++ni)
        acc[mi][ni] = __builtin_amdgcn_mfma_f32_16x16x32_bf16(
            af[mi], bfr[ni], acc[mi][ni], 0, 0, 0);
  }
#undef GSTAGE

  // ---- epilogue: write fragment-ordered k_buf / v_buf (8B per acc frag row)
  if (blockIdx.z == 0) {
    // M = d (A=wk), N = (b,t) (B=x)
    #pragma unroll
    for (int ni = 0; ni < 2; ++ni) {
      int gr = TB * 64 + wn * 32 + ni * 16 + c15;        // global x row (b,t)
      int b = gr >> 10, tc = (gr >> 6) & 15;
      int ni2 = (gr & 63) >> 4;                          // = wn*2+ni
      #pragma unroll
      for (int mi = 0; mi < 4; ++mi) {
        int d0 = TA * 128 + wm * 64 + mi * 16 + kq * 4;  // K feature dim
        int h = d0 >> 6, hd = d0 & 63;
        int half = hd >> 5, q4 = (hd >> 3) & 3, jlo = hd & 7;
        int bh = b * 16 + h;
        float4 b4 = *(const float4*)(bk + d0);
        float4 v4 = {acc[mi][ni][0] + b4.x, acc[mi][ni][1] + b4.y,
                     acc[mi][ni][2] + b4.z, acc[mi][ni][3] + b4.w};
        *(uint2*)(k_buf + ((size_t)((bh * 16 + tc) * 8 + ni2 * 2 + half)) * 512 +
                  (q4 * 16 + c15) * 8 + jlo) = pack_bf16_4(v4);
      }
    }
  } else {
    // M = (b,t) (A=x), N = d (B=wv)
    #pragma unroll
    for (int ni = 0; ni < 2; ++ni) {
      int d = TB * 64 + wn * 32 + ni * 16 + c15;         // V feature dim
      int h = d >> 6;
      int di = (d & 63) >> 4;                            // = wn*2+ni
      float bias = bv[d];
      #pragma unroll
      for (int mi = 0; mi < 4; ++mi) {
        int gr = TA * 128 + wm * 64 + mi * 16 + kq * 4;  // global x row (b,t)
        int b = gr >> 10, tc = (gr >> 6) & 15;
        int tl = gr & 63;
        int half = tl >> 5, q4 = (tl >> 3) & 3, jlo = tl & 7;
        int bh = b * 16 + h;
        float4 v4 = {acc[mi][ni][0] + bias, acc[mi][ni][1] + bias,
                     acc[mi][ni][2] + bias, acc[mi][ni][3] + bias};
        *(uint2*)(v_buf + ((size_t)((bh * 16 + tc) * 8 + di * 2 + half)) * 512 +
                  (q4 * 16 + c15) * 8 + jlo) = pack_bf16_4(v4);
      }
    }
  }
}

// ---------------------------------------------------------------------------
// flash attention, round-11: r10 structure (2 l-groups/wave, 704 blocks,
// 128 latents/block) with two stall cuts:
//  (a) ONE barrier per tc (was 2; 32->16): vmcnt(0) -> barrier ->
//      STAGE_KV(tc+1)+mask loads -> compute(tc). WAR proof: slot buf^1 is
//      staged after the barrier; its last readers (iter tc-1) lgkm-consumed
//      their ds_reads before passing that barrier. Visibility: KV(tc) was
//      staged a full compute phase earlier; the issuing wave drains
//      vmcnt(0) before the barrier. vmcnt(0) is harmless here: nothing
//      newer is in flight at the wait point (prefetch distance hides).
//  (b) pbuf doubled to [4][2048] (LDS 49152 -> still 3 blocks/CU >= the
//      2.75 the grid needs) + T15-lite interleave: softmax+write g0 ->
//      softmax+write g1 -> read+PV g0 -> read+PV g1. g1's VALU hides g0's
//      DS-write latency; g1's read hides under g0's 10 MFMA. One exposed
//      LDS round-trip per tc instead of two.
// l-sums via MFMA ones-trick. asm v_exp_f32 + sign-spread masking (r9).
// Spill sentinel: WRITE_SIZE must stay 21504.
// ---------------------------------------------------------------------------
__global__ __launch_bounds__(256, 3) void attn_kernel(
    const float* __restrict__ latent_q,            // fp32, flat (H, L, dh)
    const __hip_bfloat16* __restrict__ k_buf,      // fragment-ordered
    const __hip_bfloat16* __restrict__ v_buf,      // fragment-ordered
    const unsigned int* __restrict__ mbits,        // (b*L+l)*32 + t/32
    float* __restrict__ out) {                     // fp32 (b*L+l)*1024 + h*64+d
  __shared__ __align__(16) __hip_bfloat16 ldsK[2][4096];    // 16 KB dbuf
  __shared__ __align__(16) __hip_bfloat16 ldsV[2][4096];    // 16 KB dbuf
  __shared__ __align__(16) __hip_bfloat16 pbuf[4][2048];    // 16 KB, 2 groups

  const int tid = threadIdx.x;
  const int lane = tid & 63;
  const int w = tid >> 6;                          // wave id
  int bid = blockIdx.x;
  int xcd = bid & 7, j = bid >> 3;                 // j in [0,88)
  int bh = xcd * 8 + j / 11;                       // all blocks of one bh -> one XCD
  int sb = j % 11;                                 // 128-latent superblock
  int h = bh & 15, b = bh >> 4;
  const int q4 = lane >> 4, c15 = lane & 15;
  const int c7 = c15 & 7;
  const int l0 = sb * 128;
  const bool hasg1 = (sb < 10);                    // block-uniform
  const int lg0 = l0 + w * 16;
  const int lg1 = hasg1 ? (l0 + 64 + w * 16) : lg0;   // clamped for tail

  // ---- Q^T B-frags for both groups, pre-scaled by 16^-0.5 * log2(e)
  const float QS = 0.25f * 1.44269504089f;
  short8 qf[2][2];
  #pragma unroll
  for (int g = 0; g < 2; ++g) {
    int lg = g ? lg1 : lg0;
    const float* qp = latent_q + ((size_t)(h * L_SZ + lg + c15)) * 64 + q4 * 8;
    float4 a0 = *(const float4*)(qp);
    float4 a1 = *(const float4*)(qp + 4);
    float4 a2 = *(const float4*)(qp + 32);
    float4 a3 = *(const float4*)(qp + 36);
    a0.x *= QS; a0.y *= QS; a0.z *= QS; a0.w *= QS;
    a1.x *= QS; a1.y *= QS; a1.z *= QS; a1.w *= QS;
    a2.x *= QS; a2.y *= QS; a2.z *= QS; a2.w *= QS;
    a3.x *= QS; a3.y *= QS; a3.z *= QS; a3.w *= QS;
    short4v t0 = cvt4(a0), t1 = cvt4(a1), t2 = cvt4(a2), t3 = cvt4(a3);
    qf[g][0] = (short8){t0.x, t0.y, t0.z, t0.w, t1.x, t1.y, t1.z, t1.w};
    qf[g][1] = (short8){t2.x, t2.y, t2.z, t2.w, t3.x, t3.y, t3.z, t3.w};
  }

  const short ob16 = (short)0x3F80;                // bf16 1.0
  const short8 ones8 = (short8){ob16, ob16, ob16, ob16, ob16, ob16, ob16, ob16};
  const floatx4 zero4 = (floatx4){0.f, 0.f, 0.f, 0.f};

  floatx4 lacc[2];
  floatx4 o_acc[2][4];
  #pragma unroll
  for (int g = 0; g < 2; ++g) {
    lacc[g] = zero4;
    #pragma unroll
    for (int di = 0; di < 4; ++di) o_acc[g][di] = zero4;
  }

  const __hip_bfloat16* kb = k_buf + (size_t)bh * 65536;   // 16 tc * 8 * 512
  const __hip_bfloat16* vb = v_buf + (size_t)bh * 65536;
  __hip_bfloat16* pw = pbuf[w];
  const unsigned int* mrow0 = mbits + ((size_t)(b * L_SZ + lg0 + c15)) * 32;
  const unsigned int* mrow1 = mbits + ((size_t)(b * L_SZ + lg1 + c15)) * 32;

#define STAGE_K(sb_, tcn) do {                                              \
    const __hip_bfloat16* gk_ = kb + (size_t)(tcn) * 4096;                  \
    int o0_ = w * 512 + lane * 8;                                           \
    GLD16(gk_ + o0_,        &ldsK[sb_][w * 512]);                           \
    GLD16(gk_ + 2048 + o0_, &ldsK[sb_][2048 + w * 512]);                    \
  } while (0)
#define STAGE_V(sb_, tcn) do {                                              \
    const __hip_bfloat16* gv_ = vb + (size_t)(tcn) * 4096;                  \
    int o0_ = w * 512 + lane * 8;                                           \
    GLD16(gv_ + o0_,        &ldsV[sb_][w * 512]);                           \
    GLD16(gv_ + 2048 + o0_, &ldsV[sb_][2048 + w * 512]);                    \
  } while (0)

  STAGE_K(0, 0);                                   // prologue: KV(0), M(0)
  STAGE_V(0, 0);
  uint2 mw0 = *(const uint2*)(mrow0);
  uint2 mw1 = *(const uint2*)(mrow1);

  for (int tc = 0; tc < 16; ++tc) {
    const int buf = tc & 1;
    // ---- single sync point: KV(tc)+M(tc) landed, prev-tc reads retired
    asm volatile("s_waitcnt vmcnt(0)" ::: "memory");
    __builtin_amdgcn_s_barrier();

    uint2 mn0 = mw0, mn1 = mw1;
    if (tc < 15) {
      STAGE_K(buf ^ 1, tc + 1);                    // stage next tile (slot
      STAGE_V(buf ^ 1, tc + 1);                    //  safe: see WAR proof)
      mn0 = *(const uint2*)(mrow0 + (tc + 1) * 2);
      mn1 = *(const uint2*)(mrow1 + (tc + 1) * 2);
    }

    // ---- K A-frags from LDS once; QK^T for both groups
    short8 kf[2][4];
    #pragma unroll
    for (int half = 0; half < 2; ++half)
      #pragma unroll
      for (int ni = 0; ni < 4; ++ni)
        kf[half][ni] = *(const short8*)(&ldsK[buf][(ni * 2 + half) * 512 + lane * 8]);
    floatx4 s[2][4];
    __builtin_amdgcn_s_setprio(1);
    #pragma unroll
    for (int g = 0; g < 2; ++g) {
      #pragma unroll
      for (int ni = 0; ni < 4; ++ni)
        s[g][ni] = __builtin_amdgcn_mfma_f32_16x16x32_bf16(kf[0][ni], qf[g][0], zero4, 0, 0, 0);
      #pragma unroll
      for (int ni = 0; ni < 4; ++ni)
        s[g][ni] = __builtin_amdgcn_mfma_f32_16x16x32_bf16(kf[1][ni], qf[g][1], s[g][ni], 0, 0, 0);
    }
    __builtin_amdgcn_s_setprio(0);

    // ---- V A-frags once for both groups
    short8 vf[2][4];
    #pragma unroll
    for (int half = 0; half < 2; ++half)
      #pragma unroll
      for (int di = 0; di < 4; ++di)
        vf[half][di] = *(const short8*)(&ldsV[buf][(di * 2 + half) * 512 + lane * 8]);

    // ---- softmax+write for BOTH groups first (g1 VALU hides g0 DS write)
    #pragma unroll
    for (int g = 0; g < 2; ++g) {
      uint2 mw = g ? mw1 : mw0;
      unsigned mshx = mw.x >> (q4 * 4);            // per-lane shift paid once
      unsigned mshy = mw.y >> (q4 * 4);
      #pragma unroll
      for (int ni = 0; ni < 4; ++ni) {
        unsigned msh = (ni >= 2) ? mshy : mshx;
        float4 p4;
        #pragma unroll
        for (int r = 0; r < 4; ++r) {
          float e;
          asm("v_exp_f32 %0, %1" : "=v"(e) : "v"(s[g][ni][r]));
          const int pos = (ni & 1) * 16 + r;       // compile-time constant
          unsigned keep = (unsigned)((int)(msh << (31 - pos)) >> 31);
          ((float*)&p4)[r] = __builtin_bit_cast(
              float, __builtin_bit_cast(unsigned, e) & keep);
        }
        int pc = (ni * 2 + (q4 >> 1)) ^ c7;        // phys 16B chunk
        *(uint2*)(pw + g * 1024 + c15 * 64 + pc * 8 + (q4 & 1) * 4) = pack_bf16_4(p4);
      }
    }

    // ---- then PV for both groups (g1 read hides under g0 MFMA)
    #pragma unroll
    for (int g = 0; g < 2; ++g) {
      int pc0 = q4 ^ c7;
      short8 pf0 = *(const short8*)(pw + g * 1024 + c15 * 64 + pc0 * 8);
      short8 pf1 = *(const short8*)(pw + g * 1024 + c15 * 64 + (pc0 ^ 4) * 8);
      __builtin_amdgcn_s_setprio(1);
      #pragma unroll
      for (int di = 0; di < 4; ++di)
        o_acc[g][di] = __builtin_amdgcn_mfma_f32_16x16x32_bf16(vf[0][di], pf0, o_acc[g][di], 0, 0, 0);
      #pragma unroll
      for (int di = 0; di < 4; ++di)
        o_acc[g][di] = __builtin_amdgcn_mfma_f32_16x16x32_bf16(vf[1][di], pf1, o_acc[g][di], 0, 0, 0);
      lacc[g] = __builtin_amdgcn_mfma_f32_16x16x32_bf16(ones8, pf0, lacc[g], 0, 0, 0);
      lacc[g] = __builtin_amdgcn_mfma_f32_16x16x32_bf16(ones8, pf1, lacc[g], 0, 0, 0);
      __builtin_amdgcn_s_setprio(0);
    }

    mw0 = mn0; mw1 = mn1;
  }
#undef STAGE_K
#undef STAGE_V

  // ---- normalize, store (all rows of lacc equal l[c15]; all-masked -> 0)
  #pragma unroll
  for (int g = 0; g < 2; ++g) {
    if (g == 1 && !hasg1) break;                   // block-uniform
    int lg = g ? lg1 : lg0;
    float la = lacc[g][0];
    float inv = (la > 0.f) ? 1.f / la : 0.f;
    float* ob = out + ((size_t)(b * L_SZ + lg + c15)) * 1024 + h * 64;
    #pragma unroll
    for (int di = 0; di < 4; ++di) {
      float4 o4 = {o_acc[g][di][0] * inv, o_acc[g][di][1] * inv,
                   o_acc[g][di][2] * inv, o_acc[g][di][3] * inv};
      *(float4*)(ob + di * 16 + q4 * 4) = o4;
    }
  }
}

// ---------------------------------------------------------------------------
extern "C" void kernel_launch(void* const* d_in, const int* in_sizes, int n_in,
                              void* d_out, int out_size, void* d_ws, size_t ws_size,
                              hipStream_t stream) {
  const float* x      = (const float*)d_in[0];
  const void* ch_mask = d_in[1];
  const float* lq     = (const float*)d_in[2];
  const float* wk     = (const float*)d_in[3];
  const float* bk     = (const float*)d_in[4];
  const float* wv     = (const float*)d_in[5];
  const float* bv     = (const float*)d_in[6];
  float* out = (float*)d_out;

  // ws layout (total 16.75 MB -- proven-safe)
  char* ws = (char*)d_ws;
  unsigned int* mbits   = (unsigned int*)ws;                         // 688 KB
  __hip_bfloat16* k_buf = (__hip_bfloat16*)(ws + 786432);            // 8 MB
  __hip_bfloat16* v_buf = (__hip_bfloat16*)(ws + 786432 + 8388608);  // 8 MB

  // d_out (22 MB fp32) doubles as scratch for bf16 inputs (12 MB) -- it is
  // only written for real in attn's epilogue, after gemm_kv consumed these.
  __hip_bfloat16* xb  = (__hip_bfloat16*)d_out;                      // 8 MB
  __hip_bfloat16* wkb = xb + 4 * 1024 * 1024;                        // 2 MB
  __hip_bfloat16* wvb = wkb + 1024 * 1024;                           // 2 MB

  prep_kernel<<<2048, 256, 0, stream>>>(
      (const float4*)x, (const float4*)wk, (const float4*)wv,
      (uint2*)xb, (uint2*)wkb, (uint2*)wvb,
      ch_mask, mbits);
  gemm_kv_bf16<<<dim3(512, 1, 2), 256, 0, stream>>>(xb, wkb, wvb, bk, bv, k_buf, v_buf);

  attn_kernel<<<8 * 88, 256, 0, stream>>>(lq, k_buf, v_buf, mbits, out);
}

// Round 12
// 177.834 us; speedup vs baseline: 1.8108x; 1.0064x over previous
//
#include <hip/hip_runtime.h>
#include <hip/hip_bf16.h>

// Problem constants
#define B_SZ 4
#define T_SZ 1024
#define NH 16
#define L_SZ 1344          // 21*64
#define LT_COUNT 21        // L tiles of 64

typedef __attribute__((ext_vector_type(8))) short short8;   // 8 bf16
typedef __attribute__((ext_vector_type(4))) short short4v;  // 4 bf16
typedef __attribute__((ext_vector_type(4))) float floatx4;

typedef __attribute__((address_space(1))) const void gvoid;
typedef __attribute__((address_space(3))) void svoid;
#define GLD16(gp, lp) \
  __builtin_amdgcn_global_load_lds((gvoid*)(gp), (svoid*)(lp), 16, 0, 0)

static __device__ inline short bf16bits(float f) {
  return __builtin_bit_cast(short, __float2bfloat16(f));
}
static __device__ inline short4v cvt4(float4 v) {
  short4v r;
  r.x = bf16bits(v.x); r.y = bf16bits(v.y);
  r.z = bf16bits(v.z); r.w = bf16bits(v.w);
  return r;
}

// Fast fp32->bf16 pair pack: +0x8000 round-to-nearest(ties away) + v_perm.
// Inputs finite & bounded -> no overflow concern; error <= 0.5 ulp.
static __device__ inline unsigned pack_bf16_2(float a, float b) {
  unsigned ua = __builtin_bit_cast(unsigned, a) + 0x8000u;
  unsigned ub = __builtin_bit_cast(unsigned, b) + 0x8000u;
  return __builtin_amdgcn_perm(ub, ua, 0x07060302u);
}
static __device__ inline uint2 pack_bf16_4(float4 v) {
  return make_uint2(pack_bf16_2(v.x, v.y), pack_bf16_2(v.z, v.w));
}

// ---------------------------------------------------------------------------
// K/V fragment-ordered buffers (per bh = b*16+h, tc = t/64, frag f in [0,8)):
//  addr = ((bh*16+tc)*8 + f)*512 + lane*8 + j
//  K: f = ni2*2 + half -> K[t=tc*64+ni2*16+(lane&15)][d=half*32+(lane>>4)*8+j]
//  V: f = di*2 + half  -> V[t=tc*64+half*32+(lane>>4)*8+j][d=di*16+(lane&15)]
// => per tc, K frags are a contiguous 8 KB block (same for V).
// ---------------------------------------------------------------------------

// ---------------------------------------------------------------------------
// Fused prep, GRID-STRIDED at 2048 blocks. Virtual blocks [0,6144) convert
// x/wk/wv fp32->bf16; [6144,27648) compute mask bitwords. The mask dtype
// sniff (flag 0=int32, 1=int8, 2=int64) is done per-wave on the first 4 KB
// of the mask (64 lanes x 64 B). All-zero window -> f=2 (harmless: every
// interpretation yields all-false).
// ---------------------------------------------------------------------------
__global__ __launch_bounds__(256) void prep_kernel(
    const float4* __restrict__ x, const float4* __restrict__ wk,
    const float4* __restrict__ wv,
    uint2* __restrict__ xb, uint2* __restrict__ wkb, uint2* __restrict__ wvb,
    const void* __restrict__ mask, unsigned int* __restrict__ bits) {
  const int lane = threadIdx.x & 63;
  int f = -1;                              // per-wave mask dtype, sniffed lazily
  for (int vb = blockIdx.x; vb < 27648; vb += gridDim.x) {
    if (vb < 6144) {
      size_t i = (size_t)vb * 256 + threadIdx.x;
      if (i < 1048576)      xb[i] = pack_bf16_4(x[i]);               // x: 1M f4
      else if (i < 1310720) wkb[i - 1048576] = pack_bf16_4(wk[i - 1048576]);
      else                  wvb[i - 1310720] = pack_bf16_4(wv[i - 1310720]);
    } else {
      if (f < 0) {
        const uint4* mp = (const uint4*)mask;
        uint4 a = mp[lane * 4 + 0], b2 = mp[lane * 4 + 1];
        uint4 c = mp[lane * 4 + 2], d = mp[lane * 4 + 3];
        // bytes at i%4!=0 live in bits 8..31 of each dword
        unsigned oo = (a.x | a.y | a.z | a.w | b2.x | b2.y | b2.z | b2.w |
                       c.x | c.y | c.z | c.w | d.x | d.y | d.z | d.w) & 0xFFFFFF00u;
        // bytes at i%8==4 are byte0 of odd dwords (fields y, w)
        unsigned aa = (a.y | a.w | b2.y | b2.w | c.y | c.w | d.y | d.w) & 0xFFu;
        int anyo = __any(oo != 0), anya = __any(aa != 0);
        f = anyo ? 1 : (anya ? 0 : 2);
      }
      int idx = (vb - 6144) * 256 + threadIdx.x;
      bool v;
      if (f == 1)      v = ((const signed char*)mask)[idx] != 0;
      else if (f == 2) v = ((const long long*)mask)[idx] != 0;
      else             v = ((const int*)mask)[idx] != 0;
      unsigned long long bal = __ballot(v);
      if ((lane & 31) == 0) {
        unsigned int w = (lane & 32) ? (unsigned int)(bal >> 32) : (unsigned int)bal;
        bits[idx >> 5] = w;
      }
    }
  }
}

// ---------------------------------------------------------------------------
// GEMM K/V projection: tile 128(M)x64(N), BK=32, 1024 blocks (4/CU).
// Round-12: 3-DEEP LDS pipeline (36 KB, still 4 blocks/CU). Both prior gemm
// variants waited on loads issued only ONE short compute phase (~8 MFMA)
// earlier -- exposed L2/L3 latency x32 iters. Now tile n+2 is staged right
// after iter n's barrier and the wait is a counted vmcnt(3) (tile n+1 stays
// in flight; never 0 until the tail), so tile n's loads are 2 full phases
// old when consumed.
// Ledger (3 loads/tile): in-flight at iter-n wait = tiles {n, n+1} = 6 ->
// vmcnt(3) retires tile n. Iter 31: only t31 in flight -> vmcnt(0).
// WAR: stage targets slot (n+2)%3 = (n-1)%3; all waves passed iter-n's
// barrier having consumed their tile n-1 ds_reads (lgkm before MFMA issue).
// ---------------------------------------------------------------------------
__global__ __launch_bounds__(256, 4) void gemm_kv_bf16(
    const __hip_bfloat16* __restrict__ xb,
    const __hip_bfloat16* __restrict__ wkb, const __hip_bfloat16* __restrict__ wvb,
    const float* __restrict__ bk, const float* __restrict__ bv,
    __hip_bfloat16* __restrict__ k_buf, __hip_bfloat16* __restrict__ v_buf) {
  __shared__ __align__(16) __hip_bfloat16 ldsA[3][128 * 32];   // 3 x 8 KB
  __shared__ __align__(16) __hip_bfloat16 ldsB[3][64 * 32];    // 3 x 4 KB
  const int tid = threadIdx.x;
  const int lane = tid & 63, w = tid >> 6;
  const int wm = w & 1, wn = w >> 1;
  const int c15 = lane & 15, kq = lane >> 4;

  const __hip_bfloat16* A;
  const __hip_bfloat16* B;
  int TA, TB;
  if (blockIdx.z == 0) {            // K-proj: C^T[d][t] = Wk . X^T
    A = wkb; B = xb; TA = blockIdx.x >> 6; TB = blockIdx.x & 63;   // 8 x 64
  } else {                          // V-proj: C[t][d] = X . Wv^T
    A = xb; B = wvb; TA = blockIdx.x >> 4; TB = blockIdx.x & 15;   // 32 x 16
  }
  const __hip_bfloat16* Abase = A + (size_t)TA * 128 * 1024;
  const __hip_bfloat16* Bbase = B + (size_t)TB * 64 * 1024;

  floatx4 acc[4][2];
  #pragma unroll
  for (int i = 0; i < 4; ++i)
    #pragma unroll
    for (int j = 0; j < 2; ++j) acc[i][j] = (floatx4){0.f, 0.f, 0.f, 0.f};

#define GSTAGE(sb, kk) do {                                                  \
    int cA_ = w * 128 + lane;                                                \
    int rA_ = cA_ >> 2, gA_ = (cA_ & 3) ^ (rA_ & 3);                         \
    GLD16(Abase + (size_t)rA_ * 1024 + (kk) + gA_ * 8,                       \
          &ldsA[sb][(w * 128) * 8]);                                         \
    int cA2_ = cA_ + 64;                                                     \
    int rA2_ = cA2_ >> 2, gA2_ = (cA2_ & 3) ^ (rA2_ & 3);                    \
    GLD16(Abase + (size_t)rA2_ * 1024 + (kk) + gA2_ * 8,                     \
          &ldsA[sb][(w * 128 + 64) * 8]);                                    \
    int cB_ = w * 64 + lane;                                                 \
    int rB_ = cB_ >> 2, gB_ = (cB_ & 3) ^ (rB_ & 3);                         \
    GLD16(Bbase + (size_t)rB_ * 1024 + (kk) + gB_ * 8,                       \
          &ldsB[sb][(w * 64) * 8]);                                          \
  } while (0)

  GSTAGE(0, 0);                                        // prologue: t0, t1
  GSTAGE(1, 32);
  for (int it = 0; it < 32; ++it) {
    if (it < 31) {
      asm volatile("s_waitcnt vmcnt(3)" ::: "memory"); // tile it landed
    } else {
      asm volatile("s_waitcnt vmcnt(0)" ::: "memory");
    }
    __builtin_amdgcn_s_barrier();                      // visible; slot free
    if (it < 30) {
      const int sn = (it + 2) % 3;
      GSTAGE(sn, (it + 2) * 32);                       // stage tile it+2
    }
    const int buf = it % 3;

    short8 af[4], bfr[2];
    #pragma unroll
    for (int mi = 0; mi < 4; ++mi) {
      int row = wm * 64 + mi * 16 + c15;
      af[mi] = *(const short8*)(&ldsA[buf][row * 32 + ((kq ^ (row & 3)) * 8)]);
    }
    #pragma unroll
    for (int ni = 0; ni < 2; ++ni) {
      int row = wn * 32 + ni * 16 + c15;
      bfr[ni] = *(const short8*)(&ldsB[buf][row * 32 + ((kq ^ (row & 3)) * 8)]);
    }
    #pragma unroll
    for (int mi = 0; mi < 4; ++mi)
      #pragma unroll
      for (int ni = 0; ni < 2; ++ni)
        acc[mi][ni] = __builtin_amdgcn_mfma_f32_16x16x32_bf16(
            af[mi], bfr[ni], acc[mi][ni], 0, 0, 0);
  }
#undef GSTAGE

  // ---- epilogue: write fragment-ordered k_buf / v_buf (8B per acc frag row)
  if (blockIdx.z == 0) {
    // M = d (A=wk), N = (b,t) (B=x)
    #pragma unroll
    for (int ni = 0; ni < 2; ++ni) {
      int gr = TB * 64 + wn * 32 + ni * 16 + c15;        // global x row (b,t)
      int b = gr >> 10, tc = (gr >> 6) & 15;
      int ni2 = (gr & 63) >> 4;                          // = wn*2+ni
      #pragma unroll
      for (int mi = 0; mi < 4; ++mi) {
        int d0 = TA * 128 + wm * 64 + mi * 16 + kq * 4;  // K feature dim
        int h = d0 >> 6, hd = d0 & 63;
        int half = hd >> 5, q4 = (hd >> 3) & 3, jlo = hd & 7;
        int bh = b * 16 + h;
        float4 b4 = *(const float4*)(bk + d0);
        float4 v4 = {acc[mi][ni][0] + b4.x, acc[mi][ni][1] + b4.y,
                     acc[mi][ni][2] + b4.z, acc[mi][ni][3] + b4.w};
        *(uint2*)(k_buf + ((size_t)((bh * 16 + tc) * 8 + ni2 * 2 + half)) * 512 +
                  (q4 * 16 + c15) * 8 + jlo) = pack_bf16_4(v4);
      }
    }
  } else {
    // M = (b,t) (A=x), N = d (B=wv)
    #pragma unroll
    for (int ni = 0; ni < 2; ++ni) {
      int d = TB * 64 + wn * 32 + ni * 16 + c15;         // V feature dim
      int h = d >> 6;
      int di = (d & 63) >> 4;                            // = wn*2+ni
      float bias = bv[d];
      #pragma unroll
      for (int mi = 0; mi < 4; ++mi) {
        int gr = TA * 128 + wm * 64 + mi * 16 + kq * 4;  // global x row (b,t)
        int b = gr >> 10, tc = (gr >> 6) & 15;
        int tl = gr & 63;
        int half = tl >> 5, q4 = (tl >> 3) & 3, jlo = tl & 7;
        int bh = b * 16 + h;
        float4 v4 = {acc[mi][ni][0] + bias, acc[mi][ni][1] + bias,
                     acc[mi][ni][2] + bias, acc[mi][ni][3] + bias};
        *(uint2*)(v_buf + ((size_t)((bh * 16 + tc) * 8 + di * 2 + half)) * 512 +
                  (q4 * 16 + c15) * 8 + jlo) = pack_bf16_4(v4);
      }
    }
  }
}

// ---------------------------------------------------------------------------
// flash attention (UNCHANGED from round 11 -- 51.4 us, structural):
// 2 l-groups/wave, 704 blocks, 128 latents/block; single barrier per tc;
// pbuf[4][2048] T15-lite interleave; asm v_exp_f32 + sign-spread masking;
// l-sums via MFMA ones-trick. Spill sentinel: WRITE_SIZE must stay 21504.
// ---------------------------------------------------------------------------
__global__ __launch_bounds__(256, 3) void attn_kernel(
    const float* __restrict__ latent_q,            // fp32, flat (H, L, dh)
    const __hip_bfloat16* __restrict__ k_buf,      // fragment-ordered
    const __hip_bfloat16* __restrict__ v_buf,      // fragment-ordered
    const unsigned int* __restrict__ mbits,        // (b*L+l)*32 + t/32
    float* __restrict__ out) {                     // fp32 (b*L+l)*1024 + h*64+d
  __shared__ __align__(16) __hip_bfloat16 ldsK[2][4096];    // 16 KB dbuf
  __shared__ __align__(16) __hip_bfloat16 ldsV[2][4096];    // 16 KB dbuf
  __shared__ __align__(16) __hip_bfloat16 pbuf[4][2048];    // 16 KB, 2 groups

  const int tid = threadIdx.x;
  const int lane = tid & 63;
  const int w = tid >> 6;                          // wave id
  int bid = blockIdx.x;
  int xcd = bid & 7, j = bid >> 3;                 // j in [0,88)
  int bh = xcd * 8 + j / 11;                       // all blocks of one bh -> one XCD
  int sb = j % 11;                                 // 128-latent superblock
  int h = bh & 15, b = bh >> 4;
  const int q4 = lane >> 4, c15 = lane & 15;
  const int c7 = c15 & 7;
  const int l0 = sb * 128;
  const bool hasg1 = (sb < 10);                    // block-uniform
  const int lg0 = l0 + w * 16;
  const int lg1 = hasg1 ? (l0 + 64 + w * 16) : lg0;   // clamped for tail

  // ---- Q^T B-frags for both groups, pre-scaled by 16^-0.5 * log2(e)
  const float QS = 0.25f * 1.44269504089f;
  short8 qf[2][2];
  #pragma unroll
  for (int g = 0; g < 2; ++g) {
    int lg = g ? lg1 : lg0;
    const float* qp = latent_q + ((size_t)(h * L_SZ + lg + c15)) * 64 + q4 * 8;
    float4 a0 = *(const float4*)(qp);
    float4 a1 = *(const float4*)(qp + 4);
    float4 a2 = *(const float4*)(qp + 32);
    float4 a3 = *(const float4*)(qp + 36);
    a0.x *= QS; a0.y *= QS; a0.z *= QS; a0.w *= QS;
    a1.x *= QS; a1.y *= QS; a1.z *= QS; a1.w *= QS;
    a2.x *= QS; a2.y *= QS; a2.z *= QS; a2.w *= QS;
    a3.x *= QS; a3.y *= QS; a3.z *= QS; a3.w *= QS;
    short4v t0 = cvt4(a0), t1 = cvt4(a1), t2 = cvt4(a2), t3 = cvt4(a3);
    qf[g][0] = (short8){t0.x, t0.y, t0.z, t0.w, t1.x, t1.y, t1.z, t1.w};
    qf[g][1] = (short8){t2.x, t2.y, t2.z, t2.w, t3.x, t3.y, t3.z, t3.w};
  }

  const short ob16 = (short)0x3F80;                // bf16 1.0
  const short8 ones8 = (short8){ob16, ob16, ob16, ob16, ob16, ob16, ob16, ob16};
  const floatx4 zero4 = (floatx4){0.f, 0.f, 0.f, 0.f};

  floatx4 lacc[2];
  floatx4 o_acc[2][4];
  #pragma unroll
  for (int g = 0; g < 2; ++g) {
    lacc[g] = zero4;
    #pragma unroll
    for (int di = 0; di < 4; ++di) o_acc[g][di] = zero4;
  }

  const __hip_bfloat16* kb = k_buf + (size_t)bh * 65536;   // 16 tc * 8 * 512
  const __hip_bfloat16* vb = v_buf + (size_t)bh * 65536;
  __hip_bfloat16* pw = pbuf[w];
  const unsigned int* mrow0 = mbits + ((size_t)(b * L_SZ + lg0 + c15)) * 32;
  const unsigned int* mrow1 = mbits + ((size_t)(b * L_SZ + lg1 + c15)) * 32;

#define STAGE_K(sb_, tcn) do {                                              \
    const __hip_bfloat16* gk_ = kb + (size_t)(tcn) * 4096;                  \
    int o0_ = w * 512 + lane * 8;                                           \
    GLD16(gk_ + o0_,        &ldsK[sb_][w * 512]);                           \
    GLD16(gk_ + 2048 + o0_, &ldsK[sb_][2048 + w * 512]);                    \
  } while (0)
#define STAGE_V(sb_, tcn) do {                                              \
    const __hip_bfloat16* gv_ = vb + (size_t)(tcn) * 4096;                  \
    int o0_ = w * 512 + lane * 8;                                           \
    GLD16(gv_ + o0_,        &ldsV[sb_][w * 512]);                           \
    GLD16(gv_ + 2048 + o0_, &ldsV[sb_][2048 + w * 512]);                    \
  } while (0)

  STAGE_K(0, 0);                                   // prologue: KV(0), M(0)
  STAGE_V(0, 0);
  uint2 mw0 = *(const uint2*)(mrow0);
  uint2 mw1 = *(const uint2*)(mrow1);

  for (int tc = 0; tc < 16; ++tc) {
    const int buf = tc & 1;
    // ---- single sync point: KV(tc)+M(tc) landed, prev-tc reads retired
    asm volatile("s_waitcnt vmcnt(0)" ::: "memory");
    __builtin_amdgcn_s_barrier();

    uint2 mn0 = mw0, mn1 = mw1;
    if (tc < 15) {
      STAGE_K(buf ^ 1, tc + 1);                    // stage next tile (slot
      STAGE_V(buf ^ 1, tc + 1);                    //  safe: see WAR proof)
      mn0 = *(const uint2*)(mrow0 + (tc + 1) * 2);
      mn1 = *(const uint2*)(mrow1 + (tc + 1) * 2);
    }

    // ---- K A-frags from LDS once; QK^T for both groups
    short8 kf[2][4];
    #pragma unroll
    for (int half = 0; half < 2; ++half)
      #pragma unroll
      for (int ni = 0; ni < 4; ++ni)
        kf[half][ni] = *(const short8*)(&ldsK[buf][(ni * 2 + half) * 512 + lane * 8]);
    floatx4 s[2][4];
    __builtin_amdgcn_s_setprio(1);
    #pragma unroll
    for (int g = 0; g < 2; ++g) {
      #pragma unroll
      for (int ni = 0; ni < 4; ++ni)
        s[g][ni] = __builtin_amdgcn_mfma_f32_16x16x32_bf16(kf[0][ni], qf[g][0], zero4, 0, 0, 0);
      #pragma unroll
      for (int ni = 0; ni < 4; ++ni)
        s[g][ni] = __builtin_amdgcn_mfma_f32_16x16x32_bf16(kf[1][ni], qf[g][1], s[g][ni], 0, 0, 0);
    }
    __builtin_amdgcn_s_setprio(0);

    // ---- V A-frags once for both groups
    short8 vf[2][4];
    #pragma unroll
    for (int half = 0; half < 2; ++half)
      #pragma unroll
      for (int di = 0; di < 4; ++di)
        vf[half][di] = *(const short8*)(&ldsV[buf][(di * 2 + half) * 512 + lane * 8]);

    // ---- softmax+write for BOTH groups first (g1 VALU hides g0 DS write)
    #pragma unroll
    for (int g = 0; g < 2; ++g) {
      uint2 mw = g ? mw1 : mw0;
      unsigned mshx = mw.x >> (q4 * 4);            // per-lane shift paid once
      unsigned mshy = mw.y >> (q4 * 4);
      #pragma unroll
      for (int ni = 0; ni < 4; ++ni) {
        unsigned msh = (ni >= 2) ? mshy : mshx;
        float4 p4;
        #pragma unroll
        for (int r = 0; r < 4; ++r) {
          float e;
          asm("v_exp_f32 %0, %1" : "=v"(e) : "v"(s[g][ni][r]));
          const int pos = (ni & 1) * 16 + r;       // compile-time constant
          unsigned keep = (unsigned)((int)(msh << (31 - pos)) >> 31);
          ((float*)&p4)[r] = __builtin_bit_cast(
              float, __builtin_bit_cast(unsigned, e) & keep);
        }
        int pc = (ni * 2 + (q4 >> 1)) ^ c7;        // phys 16B chunk
        *(uint2*)(pw + g * 1024 + c15 * 64 + pc * 8 + (q4 & 1) * 4) = pack_bf16_4(p4);
      }
    }

    // ---- then PV for both groups (g1 read hides under g0 MFMA)
    #pragma unroll
    for (int g = 0; g < 2; ++g) {
      int pc0 = q4 ^ c7;
      short8 pf0 = *(const short8*)(pw + g * 1024 + c15 * 64 + pc0 * 8);
      short8 pf1 = *(const short8*)(pw + g * 1024 + c15 * 64 + (pc0 ^ 4) * 8);
      __builtin_amdgcn_s_setprio(1);
      #pragma unroll
      for (int di = 0; di < 4; ++di)
        o_acc[g][di] = __builtin_amdgcn_mfma_f32_16x16x32_bf16(vf[0][di], pf0, o_acc[g][di], 0, 0, 0);
      #pragma unroll
      for (int di = 0; di < 4; ++di)
        o_acc[g][di] = __builtin_amdgcn_mfma_f32_16x16x32_bf16(vf[1][di], pf1, o_acc[g][di], 0, 0, 0);
      lacc[g] = __builtin_amdgcn_mfma_f32_16x16x32_bf16(ones8, pf0, lacc[g], 0, 0, 0);
      lacc[g] = __builtin_amdgcn_mfma_f32_16x16x32_bf16(ones8, pf1, lacc[g], 0, 0, 0);
      __builtin_amdgcn_s_setprio(0);
    }

    mw0 = mn0; mw1 = mn1;
  }
#undef STAGE_K
#undef STAGE_V

  // ---- normalize, store (all rows of lacc equal l[c15]; all-masked -> 0)
  #pragma unroll
  for (int g = 0; g < 2; ++g) {
    if (g == 1 && !hasg1) break;                   // block-uniform
    int lg = g ? lg1 : lg0;
    float la = lacc[g][0];
    float inv = (la > 0.f) ? 1.f / la : 0.f;
    float* ob = out + ((size_t)(b * L_SZ + lg + c15)) * 1024 + h * 64;
    #pragma unroll
    for (int di = 0; di < 4; ++di) {
      float4 o4 = {o_acc[g][di][0] * inv, o_acc[g][di][1] * inv,
                   o_acc[g][di][2] * inv, o_acc[g][di][3] * inv};
      *(float4*)(ob + di * 16 + q4 * 4) = o4;
    }
  }
}

// ---------------------------------------------------------------------------
extern "C" void kernel_launch(void* const* d_in, const int* in_sizes, int n_in,
                              void* d_out, int out_size, void* d_ws, size_t ws_size,
                              hipStream_t stream) {
  const float* x      = (const float*)d_in[0];
  const void* ch_mask = d_in[1];
  const float* lq     = (const float*)d_in[2];
  const float* wk     = (const float*)d_in[3];
  const float* bk     = (const float*)d_in[4];
  const float* wv     = (const float*)d_in[5];
  const float* bv     = (const float*)d_in[6];
  float* out = (float*)d_out;

  // ws layout (total 16.75 MB -- proven-safe)
  char* ws = (char*)d_ws;
  unsigned int* mbits   = (unsigned int*)ws;                         // 688 KB
  __hip_bfloat16* k_buf = (__hip_bfloat16*)(ws + 786432);            // 8 MB
  __hip_bfloat16* v_buf = (__hip_bfloat16*)(ws + 786432 + 8388608);  // 8 MB

  // d_out (22 MB fp32) doubles as scratch for bf16 inputs (12 MB) -- it is
  // only written for real in attn's epilogue, after gemm_kv consumed these.
  __hip_bfloat16* xb  = (__hip_bfloat16*)d_out;                      // 8 MB
  __hip_bfloat16* wkb = xb + 4 * 1024 * 1024;                        // 2 MB
  __hip_bfloat16* wvb = wkb + 1024 * 1024;                           // 2 MB

  prep_kernel<<<2048, 256, 0, stream>>>(
      (const float4*)x, (const float4*)wk, (const float4*)wv,
      (uint2*)xb, (uint2*)wkb, (uint2*)wvb,
      ch_mask, mbits);
  gemm_kv_bf16<<<dim3(512, 1, 2), 256, 0, stream>>>(xb, wkb, wvb, bk, bv, k_buf, v_buf);

  attn_kernel<<<8 * 88, 256, 0, stream>>>(lq, k_buf, v_buf, mbits, out);
}